// Round 4
// baseline (1039.807 us; speedup 1.0000x reference)
//
#include <hip/hip_runtime.h>
#include <hip/hip_bf16.h>

#define N_NODES 50000
#define N_EDGES 800000
#define FDIM 64

// ---------------------------------------------------------------------------
// CSR build step 1: in-degree counts (int atomics)
// ---------------------------------------------------------------------------
__global__ void count_kernel(const int* __restrict__ dst, int* __restrict__ counts) {
    int e = blockIdx.x * blockDim.x + threadIdx.x;
    if (e < N_EDGES) atomicAdd(&counts[dst[e]], 1);
}

// ---------------------------------------------------------------------------
// CSR build step 2: exclusive prefix sum -> row_start[0..N] and cursor[0..N-1]
// single block, 1024 threads, wave-shfl scan
// ---------------------------------------------------------------------------
__global__ __launch_bounds__(1024)
void scan_kernel(const int* __restrict__ counts, int* __restrict__ row_start,
                 int* __restrict__ cursor) {
    __shared__ int wincl[16];
    __shared__ int wtot[16];
    __shared__ int s_carry;
    const int lane = threadIdx.x & 63;
    const int w = threadIdx.x >> 6;
    if (threadIdx.x == 0) s_carry = 0;
    __syncthreads();
    for (int base = 0; base < N_NODES; base += 1024) {
        int i = base + threadIdx.x;
        int v = (i < N_NODES) ? counts[i] : 0;
        int sv = v;
#pragma unroll
        for (int off = 1; off < 64; off <<= 1) {
            int t = __shfl_up(sv, off, 64);
            if (lane >= off) sv += t;
        }
        if (lane == 63) wtot[w] = sv;
        __syncthreads();
        if (w == 0) {
            int t = (lane < 16) ? wtot[lane] : 0;
#pragma unroll
            for (int off = 1; off < 16; off <<= 1) {
                int u = __shfl_up(t, off, 64);
                if (lane >= off) t += u;
            }
            if (lane < 16) wincl[lane] = t;
        }
        __syncthreads();
        int woff = (w == 0) ? 0 : wincl[w - 1];
        int excl = s_carry + woff + sv - v;
        if (i < N_NODES) { row_start[i] = excl; cursor[i] = excl; }
        __syncthreads();  // all reads of s_carry done
        if (threadIdx.x == 1023) s_carry += woff + sv;
        __syncthreads();
    }
    if (threadIdx.x == 0) row_start[N_NODES] = s_carry;
}

// ---------------------------------------------------------------------------
// CSR build step 3: bucket-fill sources by destination
// ---------------------------------------------------------------------------
__global__ void fill_kernel(const int* __restrict__ src, const int* __restrict__ dst,
                            int* __restrict__ cursor, int* __restrict__ csr_src) {
    int e = blockIdx.x * blockDim.x + threadIdx.x;
    if (e < N_EDGES) {
        int d = dst[e];
        int pos = atomicAdd(&cursor[d], 1);
        csr_src[pos] = src[e];
    }
}

// ---------------------------------------------------------------------------
// gather: one wave per node, lane = column. NO LDS -> 32 waves/CU.
// edge loop unrolled x8 -> 8 row-loads in flight per wave.
// writes m[n][j] = (x[n][j] + sum_neighbors) / (deg+1)
// ---------------------------------------------------------------------------
__global__ __launch_bounds__(256)
void gather_kernel(const float* __restrict__ x,
                   const int* __restrict__ row_start,
                   const int* __restrict__ csr_src,
                   float* __restrict__ m) {
    const int g = threadIdx.x >> 6;
    const int j = threadIdx.x & 63;
    const int n = blockIdx.x * 4 + g;          // grid = 12500 * 4 = 50000 exactly

    const int rs = row_start[n];
    const int re = row_start[n + 1];

    float sum = x[n * FDIM + j];               // self-loop
    int e = rs;
    for (; e + 8 <= re; e += 8) {
        int s0 = csr_src[e + 0], s1 = csr_src[e + 1];
        int s2 = csr_src[e + 2], s3 = csr_src[e + 3];
        int s4 = csr_src[e + 4], s5 = csr_src[e + 5];
        int s6 = csr_src[e + 6], s7 = csr_src[e + 7];
        float v0 = x[s0 * FDIM + j], v1 = x[s1 * FDIM + j];
        float v2 = x[s2 * FDIM + j], v3 = x[s3 * FDIM + j];
        float v4 = x[s4 * FDIM + j], v5 = x[s5 * FDIM + j];
        float v6 = x[s6 * FDIM + j], v7 = x[s7 * FDIM + j];
        sum += ((v0 + v1) + (v2 + v3)) + ((v4 + v5) + (v6 + v7));
    }
    for (; e < re; ++e) {
        sum += x[csr_src[e] * FDIM + j];
    }
    m[n * FDIM + j] = sum / (float)(re - rs + 1);
}

// ---------------------------------------------------------------------------
// transform: out = relu( m @ Wl + bl + x @ Wr )
// block = 256 (4 waves), 32 nodes per block, 8 nodes per wave.
// weight LDS reads amortized over 8 nodes; m/x rows are same-address
// float4 LDS broadcasts (conflict-free fast path).
// ---------------------------------------------------------------------------
__global__ __launch_bounds__(256)
void transform_kernel(const float* __restrict__ m,
                      const float* __restrict__ x,
                      const float* __restrict__ Wl,
                      const float* __restrict__ bl,
                      const float* __restrict__ Wr,
                      float* __restrict__ out) {
    __shared__ float sWl[FDIM * FDIM];
    __shared__ float sWr[FDIM * FDIM];
    __shared__ float sbl[FDIM];
    __shared__ __align__(16) float smt[32][FDIM];
    __shared__ __align__(16) float sxt[32][FDIM];

    for (int i = threadIdx.x; i < FDIM * FDIM; i += 256) {
        sWl[i] = Wl[i];
        sWr[i] = Wr[i];
    }
    if (threadIdx.x < FDIM) sbl[threadIdx.x] = bl[threadIdx.x];

    const int w = threadIdx.x >> 6;
    const int j = threadIdx.x & 63;
    const int base = blockIdx.x * 32;

    for (int r = w; r < 32; r += 4) {
        int n = base + r;
        if (n < N_NODES) {
            smt[r][j] = m[n * FDIM + j];
            sxt[r][j] = x[n * FDIM + j];
        }
    }
    __syncthreads();

    float acc[8];
#pragma unroll
    for (int r = 0; r < 8; ++r) acc[r] = sbl[j];

    const int row0 = w * 8;
#pragma unroll
    for (int k = 0; k < FDIM; k += 4) {
        float wl0 = sWl[(k + 0) * FDIM + j];
        float wl1 = sWl[(k + 1) * FDIM + j];
        float wl2 = sWl[(k + 2) * FDIM + j];
        float wl3 = sWl[(k + 3) * FDIM + j];
        float wr0 = sWr[(k + 0) * FDIM + j];
        float wr1 = sWr[(k + 1) * FDIM + j];
        float wr2 = sWr[(k + 2) * FDIM + j];
        float wr3 = sWr[(k + 3) * FDIM + j];
#pragma unroll
        for (int r = 0; r < 8; ++r) {
            float4 m4 = *(const float4*)&smt[row0 + r][k];
            float4 x4 = *(const float4*)&sxt[row0 + r][k];
            float a = acc[r];
            a = fmaf(m4.x, wl0, a);
            a = fmaf(x4.x, wr0, a);
            a = fmaf(m4.y, wl1, a);
            a = fmaf(x4.y, wr1, a);
            a = fmaf(m4.z, wl2, a);
            a = fmaf(x4.z, wr2, a);
            a = fmaf(m4.w, wl3, a);
            a = fmaf(x4.w, wr3, a);
            acc[r] = a;
        }
    }

#pragma unroll
    for (int r = 0; r < 8; ++r) {
        int n = base + row0 + r;
        if (n < N_NODES) out[n * FDIM + j] = fmaxf(acc[r], 0.0f);
    }
}

// ---------------------------------------------------------------------------
extern "C" void kernel_launch(void* const* d_in, const int* in_sizes, int n_in,
                              void* d_out, int out_size, void* d_ws, size_t ws_size,
                              hipStream_t stream) {
    const float* x0  = (const float*)d_in[0];
    const int*   ei  = (const int*)d_in[1];
    const float* Wl0 = (const float*)d_in[2];
    const float* bl0 = (const float*)d_in[3];
    const float* Wr0 = (const float*)d_in[4];
    const float* Wl1 = (const float*)d_in[5];
    const float* bl1 = (const float*)d_in[6];
    const float* Wr1 = (const float*)d_in[7];
    float* out = (float*)d_out;

    const int* src = ei;            // edge_index[0]
    const int* dst = ei + N_EDGES;  // edge_index[1]

    // workspace: counts[N] | row_start[N+1] | cursor[N] | csr_src[E] | m[N*64] | h1[N*64]
    int* counts    = (int*)d_ws;
    int* row_start = counts + N_NODES;
    int* cursor    = row_start + N_NODES + 1;
    int* csr_src   = cursor + N_NODES;
    float* mbuf    = (float*)(csr_src + N_EDGES);
    float* h1      = mbuf + (size_t)N_NODES * FDIM;

    hipMemsetAsync(counts, 0, N_NODES * sizeof(int), stream);
    count_kernel<<<(N_EDGES + 255) / 256, 256, 0, stream>>>(dst, counts);
    scan_kernel<<<1, 1024, 0, stream>>>(counts, row_start, cursor);
    fill_kernel<<<(N_EDGES + 255) / 256, 256, 0, stream>>>(src, dst, cursor, csr_src);

    const int tf_blocks = (N_NODES + 31) / 32;

    // ---- layer 0 ----
    gather_kernel<<<N_NODES / 4, 256, 0, stream>>>(x0, row_start, csr_src, mbuf);
    transform_kernel<<<tf_blocks, 256, 0, stream>>>(mbuf, x0, Wl0, bl0, Wr0, h1);

    // ---- layer 1 ----
    gather_kernel<<<N_NODES / 4, 256, 0, stream>>>(h1, row_start, csr_src, mbuf);
    transform_kernel<<<tf_blocks, 256, 0, stream>>>(mbuf, h1, Wl1, bl1, Wr1, out);
}

// Round 5
// 343.618 us; speedup vs baseline: 3.0261x; 3.0261x over previous
//
#include <hip/hip_runtime.h>
#include <hip/hip_bf16.h>

#define N_NODES 50000
#define N_EDGES 800000
#define FDIM 64

// ---------------------------------------------------------------------------
// CSR build step 1: in-degree counts (int atomics)
// ---------------------------------------------------------------------------
__global__ void count_kernel(const int* __restrict__ dst, int* __restrict__ counts) {
    int e = blockIdx.x * blockDim.x + threadIdx.x;
    if (e < N_EDGES) atomicAdd(&counts[dst[e]], 1);
}

// ---------------------------------------------------------------------------
// CSR build step 2: exclusive prefix sum -> row_start[0..N] and cursor[0..N-1]
// single block, 1024 threads, wave-shfl scan
// ---------------------------------------------------------------------------
__global__ __launch_bounds__(1024)
void scan_kernel(const int* __restrict__ counts, int* __restrict__ row_start,
                 int* __restrict__ cursor) {
    __shared__ int wincl[16];
    __shared__ int wtot[16];
    __shared__ int s_carry;
    const int lane = threadIdx.x & 63;
    const int w = threadIdx.x >> 6;
    if (threadIdx.x == 0) s_carry = 0;
    __syncthreads();
    for (int base = 0; base < N_NODES; base += 1024) {
        int i = base + threadIdx.x;
        int v = (i < N_NODES) ? counts[i] : 0;
        int sv = v;
#pragma unroll
        for (int off = 1; off < 64; off <<= 1) {
            int t = __shfl_up(sv, off, 64);
            if (lane >= off) sv += t;
        }
        if (lane == 63) wtot[w] = sv;
        __syncthreads();
        if (w == 0) {
            int t = (lane < 16) ? wtot[lane] : 0;
#pragma unroll
            for (int off = 1; off < 16; off <<= 1) {
                int u = __shfl_up(t, off, 64);
                if (lane >= off) t += u;
            }
            if (lane < 16) wincl[lane] = t;
        }
        __syncthreads();
        int woff = (w == 0) ? 0 : wincl[w - 1];
        int excl = s_carry + woff + sv - v;
        if (i < N_NODES) { row_start[i] = excl; cursor[i] = excl; }
        __syncthreads();  // all reads of s_carry done
        if (threadIdx.x == 1023) s_carry += woff + sv;
        __syncthreads();
    }
    if (threadIdx.x == 0) row_start[N_NODES] = s_carry;
}

// ---------------------------------------------------------------------------
// CSR build step 3: bucket-fill sources by destination
// ---------------------------------------------------------------------------
__global__ void fill_kernel(const int* __restrict__ src, const int* __restrict__ dst,
                            int* __restrict__ cursor, int* __restrict__ csr_src) {
    int e = blockIdx.x * blockDim.x + threadIdx.x;
    if (e < N_EDGES) {
        int d = dst[e];
        int pos = atomicAdd(&cursor[d], 1);
        csr_src[pos] = src[e];
    }
}

// ---------------------------------------------------------------------------
// gather: one wave per node, lane = column. NO LDS -> full occupancy.
// edge loop unrolled x8 -> 8 row-loads in flight per wave.
// writes m[n][j] = (x[n][j] + sum_neighbors) / (deg+1)
// ---------------------------------------------------------------------------
__global__ __launch_bounds__(256)
void gather_kernel(const float* __restrict__ x,
                   const int* __restrict__ row_start,
                   const int* __restrict__ csr_src,
                   float* __restrict__ m) {
    const int g = threadIdx.x >> 6;
    const int j = threadIdx.x & 63;
    const int n = blockIdx.x * 4 + g;          // grid = 12500 * 4 = 50000 exactly

    const int rs = row_start[n];
    const int re = row_start[n + 1];

    float sum = x[n * FDIM + j];               // self-loop
    int e = rs;
    for (; e + 8 <= re; e += 8) {
        int s0 = csr_src[e + 0], s1 = csr_src[e + 1];
        int s2 = csr_src[e + 2], s3 = csr_src[e + 3];
        int s4 = csr_src[e + 4], s5 = csr_src[e + 5];
        int s6 = csr_src[e + 6], s7 = csr_src[e + 7];
        float v0 = x[s0 * FDIM + j], v1 = x[s1 * FDIM + j];
        float v2 = x[s2 * FDIM + j], v3 = x[s3 * FDIM + j];
        float v4 = x[s4 * FDIM + j], v5 = x[s5 * FDIM + j];
        float v6 = x[s6 * FDIM + j], v7 = x[s7 * FDIM + j];
        sum += ((v0 + v1) + (v2 + v3)) + ((v4 + v5) + (v6 + v7));
    }
    for (; e < re; ++e) {
        sum += x[csr_src[e] * FDIM + j];
    }
    m[n * FDIM + j] = sum / (float)(re - rs + 1);
}

// ---------------------------------------------------------------------------
// transform: out = relu( m @ Wl + bl + x @ Wr )
// block = 256 (4 waves), 16 nodes per block, 4 nodes per wave (acc0..acc3
// scalars), k-group loop with LIMITED unroll (2) to keep VGPRs < 128.
// grid = 3125 blocks * 16 nodes = 50000 exactly (no bounds checks).
// ---------------------------------------------------------------------------
__global__ __launch_bounds__(256)
void transform_kernel(const float* __restrict__ m,
                      const float* __restrict__ x,
                      const float* __restrict__ Wl,
                      const float* __restrict__ bl,
                      const float* __restrict__ Wr,
                      float* __restrict__ out) {
    __shared__ float sWl[FDIM * FDIM];
    __shared__ float sWr[FDIM * FDIM];
    __shared__ float sbl[FDIM];
    __shared__ __align__(16) float smt[16][FDIM];
    __shared__ __align__(16) float sxt[16][FDIM];

    for (int i = threadIdx.x; i < FDIM * FDIM; i += 256) {
        sWl[i] = Wl[i];
        sWr[i] = Wr[i];
    }
    if (threadIdx.x < FDIM) sbl[threadIdx.x] = bl[threadIdx.x];

    const int w = threadIdx.x >> 6;
    const int j = threadIdx.x & 63;
    const int base = blockIdx.x * 16;

    for (int r = w; r < 16; r += 4) {
        int n = base + r;
        smt[r][j] = m[n * FDIM + j];
        sxt[r][j] = x[n * FDIM + j];
    }
    __syncthreads();

    const int row0 = w * 4;
    float acc0 = sbl[j];
    float acc1 = acc0, acc2 = acc0, acc3 = acc0;

#pragma unroll 2
    for (int k = 0; k < FDIM; k += 4) {
        float wl0 = sWl[(k + 0) * FDIM + j];
        float wl1 = sWl[(k + 1) * FDIM + j];
        float wl2 = sWl[(k + 2) * FDIM + j];
        float wl3 = sWl[(k + 3) * FDIM + j];
        float wr0 = sWr[(k + 0) * FDIM + j];
        float wr1 = sWr[(k + 1) * FDIM + j];
        float wr2 = sWr[(k + 2) * FDIM + j];
        float wr3 = sWr[(k + 3) * FDIM + j];

        float4 ma, xa;
        ma = *(const float4*)&smt[row0 + 0][k];
        xa = *(const float4*)&sxt[row0 + 0][k];
        acc0 = fmaf(ma.x, wl0, acc0); acc0 = fmaf(xa.x, wr0, acc0);
        acc0 = fmaf(ma.y, wl1, acc0); acc0 = fmaf(xa.y, wr1, acc0);
        acc0 = fmaf(ma.z, wl2, acc0); acc0 = fmaf(xa.z, wr2, acc0);
        acc0 = fmaf(ma.w, wl3, acc0); acc0 = fmaf(xa.w, wr3, acc0);

        ma = *(const float4*)&smt[row0 + 1][k];
        xa = *(const float4*)&sxt[row0 + 1][k];
        acc1 = fmaf(ma.x, wl0, acc1); acc1 = fmaf(xa.x, wr0, acc1);
        acc1 = fmaf(ma.y, wl1, acc1); acc1 = fmaf(xa.y, wr1, acc1);
        acc1 = fmaf(ma.z, wl2, acc1); acc1 = fmaf(xa.z, wr2, acc1);
        acc1 = fmaf(ma.w, wl3, acc1); acc1 = fmaf(xa.w, wr3, acc1);

        ma = *(const float4*)&smt[row0 + 2][k];
        xa = *(const float4*)&sxt[row0 + 2][k];
        acc2 = fmaf(ma.x, wl0, acc2); acc2 = fmaf(xa.x, wr0, acc2);
        acc2 = fmaf(ma.y, wl1, acc2); acc2 = fmaf(xa.y, wr1, acc2);
        acc2 = fmaf(ma.z, wl2, acc2); acc2 = fmaf(xa.z, wr2, acc2);
        acc2 = fmaf(ma.w, wl3, acc2); acc2 = fmaf(xa.w, wr3, acc2);

        ma = *(const float4*)&smt[row0 + 3][k];
        xa = *(const float4*)&sxt[row0 + 3][k];
        acc3 = fmaf(ma.x, wl0, acc3); acc3 = fmaf(xa.x, wr0, acc3);
        acc3 = fmaf(ma.y, wl1, acc3); acc3 = fmaf(xa.y, wr1, acc3);
        acc3 = fmaf(ma.z, wl2, acc3); acc3 = fmaf(xa.z, wr2, acc3);
        acc3 = fmaf(ma.w, wl3, acc3); acc3 = fmaf(xa.w, wr3, acc3);
    }

    out[(base + row0 + 0) * FDIM + j] = fmaxf(acc0, 0.0f);
    out[(base + row0 + 1) * FDIM + j] = fmaxf(acc1, 0.0f);
    out[(base + row0 + 2) * FDIM + j] = fmaxf(acc2, 0.0f);
    out[(base + row0 + 3) * FDIM + j] = fmaxf(acc3, 0.0f);
}

// ---------------------------------------------------------------------------
extern "C" void kernel_launch(void* const* d_in, const int* in_sizes, int n_in,
                              void* d_out, int out_size, void* d_ws, size_t ws_size,
                              hipStream_t stream) {
    const float* x0  = (const float*)d_in[0];
    const int*   ei  = (const int*)d_in[1];
    const float* Wl0 = (const float*)d_in[2];
    const float* bl0 = (const float*)d_in[3];
    const float* Wr0 = (const float*)d_in[4];
    const float* Wl1 = (const float*)d_in[5];
    const float* bl1 = (const float*)d_in[6];
    const float* Wr1 = (const float*)d_in[7];
    float* out = (float*)d_out;

    const int* src = ei;            // edge_index[0]
    const int* dst = ei + N_EDGES;  // edge_index[1]

    // workspace: counts[N] | row_start[N+1] | cursor[N] | csr_src[E] | m[N*64] | h1[N*64]
    int* counts    = (int*)d_ws;
    int* row_start = counts + N_NODES;
    int* cursor    = row_start + N_NODES + 1;
    int* csr_src   = cursor + N_NODES;
    float* mbuf    = (float*)(csr_src + N_EDGES);
    float* h1      = mbuf + (size_t)N_NODES * FDIM;

    hipMemsetAsync(counts, 0, N_NODES * sizeof(int), stream);
    count_kernel<<<(N_EDGES + 255) / 256, 256, 0, stream>>>(dst, counts);
    scan_kernel<<<1, 1024, 0, stream>>>(counts, row_start, cursor);
    fill_kernel<<<(N_EDGES + 255) / 256, 256, 0, stream>>>(src, dst, cursor, csr_src);

    const int tf_blocks = N_NODES / 16;   // 3125 * 16 = 50000 exactly

    // ---- layer 0 ----
    gather_kernel<<<N_NODES / 4, 256, 0, stream>>>(x0, row_start, csr_src, mbuf);
    transform_kernel<<<tf_blocks, 256, 0, stream>>>(mbuf, x0, Wl0, bl0, Wr0, h1);

    // ---- layer 1 ----
    gather_kernel<<<N_NODES / 4, 256, 0, stream>>>(h1, row_start, csr_src, mbuf);
    transform_kernel<<<tf_blocks, 256, 0, stream>>>(mbuf, h1, Wl1, bl1, Wr1, out);
}

// Round 6
// 301.634 us; speedup vs baseline: 3.4473x; 1.1392x over previous
//
#include <hip/hip_runtime.h>
#include <hip/hip_bf16.h>

#define N_NODES 50000
#define N_EDGES 800000
#define FDIM 64
#define SCAN_NB ((N_NODES + 255) / 256)   // 196 blocks

// ---------------------------------------------------------------------------
// CSR build step 1: in-degree counts (int atomics)
// ---------------------------------------------------------------------------
__global__ void count_kernel(const int* __restrict__ dst, int* __restrict__ counts) {
    int e = blockIdx.x * blockDim.x + threadIdx.x;
    if (e < N_EDGES) atomicAdd(&counts[dst[e]], 1);
}

// ---------------------------------------------------------------------------
// CSR scan A: per-block sums of counts -> bsum[196]
// ---------------------------------------------------------------------------
__global__ __launch_bounds__(256)
void scan_reduce_kernel(const int* __restrict__ counts, int* __restrict__ bsum) {
    __shared__ int wsum[4];
    int i = blockIdx.x * 256 + threadIdx.x;
    int v = (i < N_NODES) ? counts[i] : 0;
#pragma unroll
    for (int off = 32; off > 0; off >>= 1) v += __shfl_xor(v, off, 64);
    const int w = threadIdx.x >> 6;
    if ((threadIdx.x & 63) == 0) wsum[w] = v;
    __syncthreads();
    if (threadIdx.x == 0) bsum[blockIdx.x] = wsum[0] + wsum[1] + wsum[2] + wsum[3];
}

// ---------------------------------------------------------------------------
// CSR scan B: exclusive scan of bsum[196] -> boff[196]; total -> row_start[N]
// single block of 256
// ---------------------------------------------------------------------------
__global__ __launch_bounds__(256)
void scan_sums_kernel(const int* __restrict__ bsum, int* __restrict__ boff,
                      int* __restrict__ row_start) {
    __shared__ int wtot[4];
    __shared__ int wincl[4];
    const int t = threadIdx.x;
    const int lane = t & 63;
    const int w = t >> 6;
    int v = (t < SCAN_NB) ? bsum[t] : 0;
    int sv = v;
#pragma unroll
    for (int off = 1; off < 64; off <<= 1) {
        int u = __shfl_up(sv, off, 64);
        if (lane >= off) sv += u;
    }
    if (lane == 63) wtot[w] = sv;
    __syncthreads();
    if (w == 0 && lane < 4) {
        int a = wtot[lane];
        int incl = a;
        if (lane >= 1) incl += wtot[lane - 1];
        if (lane >= 2) incl += (lane >= 2 ? wtot[lane - 2] : 0);
        if (lane >= 3) incl += (lane >= 3 ? wtot[lane - 3] : 0);
        wincl[lane] = incl;
    }
    __syncthreads();
    int excl = (w ? wincl[w - 1] : 0) + sv - v;
    if (t < SCAN_NB) boff[t] = excl;
    if (t == SCAN_NB - 1) row_start[N_NODES] = excl + v;
}

// ---------------------------------------------------------------------------
// CSR scan C: apply — row_start[i] = cursor[i] = boff[b] + excl-scan-in-block
// ---------------------------------------------------------------------------
__global__ __launch_bounds__(256)
void scan_apply_kernel(const int* __restrict__ counts, const int* __restrict__ boff,
                       int* __restrict__ row_start, int* __restrict__ cursor) {
    __shared__ int wtot[4];
    __shared__ int wincl[4];
    const int t = threadIdx.x;
    const int lane = t & 63;
    const int w = t >> 6;
    int i = blockIdx.x * 256 + t;
    int v = (i < N_NODES) ? counts[i] : 0;
    int sv = v;
#pragma unroll
    for (int off = 1; off < 64; off <<= 1) {
        int u = __shfl_up(sv, off, 64);
        if (lane >= off) sv += u;
    }
    if (lane == 63) wtot[w] = sv;
    __syncthreads();
    if (w == 0 && lane < 4) {
        int incl = 0;
#pragma unroll
        for (int k = 0; k < 4; ++k)
            if (k <= lane) incl += wtot[k];
        wincl[lane] = incl;
    }
    __syncthreads();
    int excl = (w ? wincl[w - 1] : 0) + sv - v;
    int val = boff[blockIdx.x] + excl;
    if (i < N_NODES) { row_start[i] = val; cursor[i] = val; }
}

// ---------------------------------------------------------------------------
// CSR fill: bucket sources by destination; nontemporal scattered store
// ---------------------------------------------------------------------------
__global__ void fill_kernel(const int* __restrict__ src, const int* __restrict__ dst,
                            int* __restrict__ cursor, int* __restrict__ csr_src) {
    int e = blockIdx.x * blockDim.x + threadIdx.x;
    if (e < N_EDGES) {
        int d = dst[e];
        int pos = atomicAdd(&cursor[d], 1);
        __builtin_nontemporal_store(src[e], &csr_src[pos]);
    }
}

// ---------------------------------------------------------------------------
// gather: one wave per node; lane = quad q (edge slot) x col-quad c (float4).
// Each x-row read is 16 lanes x 16B = 256B; 4 rows per wave-instruction,
// x4 unroll -> 16 row-loads in flight per wave. No LDS -> full occupancy.
// m[n][:] = (x[n][:] + sum_neighbors) / (deg+1)
// ---------------------------------------------------------------------------
__global__ __launch_bounds__(256)
void gather_kernel(const float* __restrict__ x,
                   const int* __restrict__ row_start,
                   const int* __restrict__ csr_src,
                   float* __restrict__ m) {
    const int w = threadIdx.x >> 6;
    const int lane = threadIdx.x & 63;
    const int q = lane >> 4;          // edge slot 0..3
    const int c = lane & 15;          // column quad: cols 4c..4c+3
    const int n = blockIdx.x * 4 + w; // grid = 12500*4 = 50000 exactly

    const int rs = row_start[n];
    const int re = row_start[n + 1];

    float4 sum = make_float4(0.f, 0.f, 0.f, 0.f);
    if (q == 0) sum = ((const float4*)(x + (size_t)n * FDIM))[c];   // self-loop

    int idx = rs + q;
    for (; idx + 12 < re; idx += 16) {
        int s0 = csr_src[idx + 0];
        int s1 = csr_src[idx + 4];
        int s2 = csr_src[idx + 8];
        int s3 = csr_src[idx + 12];
        float4 v0 = ((const float4*)(x + (size_t)s0 * FDIM))[c];
        float4 v1 = ((const float4*)(x + (size_t)s1 * FDIM))[c];
        float4 v2 = ((const float4*)(x + (size_t)s2 * FDIM))[c];
        float4 v3 = ((const float4*)(x + (size_t)s3 * FDIM))[c];
        sum.x += (v0.x + v1.x) + (v2.x + v3.x);
        sum.y += (v0.y + v1.y) + (v2.y + v3.y);
        sum.z += (v0.z + v1.z) + (v2.z + v3.z);
        sum.w += (v0.w + v1.w) + (v2.w + v3.w);
    }
    for (; idx < re; idx += 4) {
        int s = csr_src[idx];
        float4 v = ((const float4*)(x + (size_t)s * FDIM))[c];
        sum.x += v.x; sum.y += v.y; sum.z += v.z; sum.w += v.w;
    }

    // cross-quad butterfly (lanes c, c+16, c+32, c+48 hold same columns)
#pragma unroll
    for (int off = 16; off < 64; off <<= 1) {
        sum.x += __shfl_xor(sum.x, off, 64);
        sum.y += __shfl_xor(sum.y, off, 64);
        sum.z += __shfl_xor(sum.z, off, 64);
        sum.w += __shfl_xor(sum.w, off, 64);
    }

    if (q == 0) {
        float inv = 1.0f / (float)(re - rs + 1);
        float4 r = make_float4(sum.x * inv, sum.y * inv, sum.z * inv, sum.w * inv);
        ((float4*)(m + (size_t)n * FDIM))[c] = r;
    }
}

// ---------------------------------------------------------------------------
// transform: out = relu( m @ Wl + bl + x @ Wr )
// block = 256 (4 waves), 16 nodes/block, 4 nodes/wave, unroll 2 (VGPR < 128)
// ---------------------------------------------------------------------------
__global__ __launch_bounds__(256)
void transform_kernel(const float* __restrict__ m,
                      const float* __restrict__ x,
                      const float* __restrict__ Wl,
                      const float* __restrict__ bl,
                      const float* __restrict__ Wr,
                      float* __restrict__ out) {
    __shared__ float sWl[FDIM * FDIM];
    __shared__ float sWr[FDIM * FDIM];
    __shared__ float sbl[FDIM];
    __shared__ __align__(16) float smt[16][FDIM];
    __shared__ __align__(16) float sxt[16][FDIM];

    for (int i = threadIdx.x; i < FDIM * FDIM; i += 256) {
        sWl[i] = Wl[i];
        sWr[i] = Wr[i];
    }
    if (threadIdx.x < FDIM) sbl[threadIdx.x] = bl[threadIdx.x];

    const int w = threadIdx.x >> 6;
    const int j = threadIdx.x & 63;
    const int base = blockIdx.x * 16;

    for (int r = w; r < 16; r += 4) {
        int n = base + r;
        smt[r][j] = m[n * FDIM + j];
        sxt[r][j] = x[n * FDIM + j];
    }
    __syncthreads();

    const int row0 = w * 4;
    float acc0 = sbl[j];
    float acc1 = acc0, acc2 = acc0, acc3 = acc0;

#pragma unroll 2
    for (int k = 0; k < FDIM; k += 4) {
        float wl0 = sWl[(k + 0) * FDIM + j];
        float wl1 = sWl[(k + 1) * FDIM + j];
        float wl2 = sWl[(k + 2) * FDIM + j];
        float wl3 = sWl[(k + 3) * FDIM + j];
        float wr0 = sWr[(k + 0) * FDIM + j];
        float wr1 = sWr[(k + 1) * FDIM + j];
        float wr2 = sWr[(k + 2) * FDIM + j];
        float wr3 = sWr[(k + 3) * FDIM + j];

        float4 ma, xa;
        ma = *(const float4*)&smt[row0 + 0][k];
        xa = *(const float4*)&sxt[row0 + 0][k];
        acc0 = fmaf(ma.x, wl0, acc0); acc0 = fmaf(xa.x, wr0, acc0);
        acc0 = fmaf(ma.y, wl1, acc0); acc0 = fmaf(xa.y, wr1, acc0);
        acc0 = fmaf(ma.z, wl2, acc0); acc0 = fmaf(xa.z, wr2, acc0);
        acc0 = fmaf(ma.w, wl3, acc0); acc0 = fmaf(xa.w, wr3, acc0);

        ma = *(const float4*)&smt[row0 + 1][k];
        xa = *(const float4*)&sxt[row0 + 1][k];
        acc1 = fmaf(ma.x, wl0, acc1); acc1 = fmaf(xa.x, wr0, acc1);
        acc1 = fmaf(ma.y, wl1, acc1); acc1 = fmaf(xa.y, wr1, acc1);
        acc1 = fmaf(ma.z, wl2, acc1); acc1 = fmaf(xa.z, wr2, acc1);
        acc1 = fmaf(ma.w, wl3, acc1); acc1 = fmaf(xa.w, wr3, acc1);

        ma = *(const float4*)&smt[row0 + 2][k];
        xa = *(const float4*)&sxt[row0 + 2][k];
        acc2 = fmaf(ma.x, wl0, acc2); acc2 = fmaf(xa.x, wr0, acc2);
        acc2 = fmaf(ma.y, wl1, acc2); acc2 = fmaf(xa.y, wr1, acc2);
        acc2 = fmaf(ma.z, wl2, acc2); acc2 = fmaf(xa.z, wr2, acc2);
        acc2 = fmaf(ma.w, wl3, acc2); acc2 = fmaf(xa.w, wr3, acc2);

        ma = *(const float4*)&smt[row0 + 3][k];
        xa = *(const float4*)&sxt[row0 + 3][k];
        acc3 = fmaf(ma.x, wl0, acc3); acc3 = fmaf(xa.x, wr0, acc3);
        acc3 = fmaf(ma.y, wl1, acc3); acc3 = fmaf(xa.y, wr1, acc3);
        acc3 = fmaf(ma.z, wl2, acc3); acc3 = fmaf(xa.z, wr2, acc3);
        acc3 = fmaf(ma.w, wl3, acc3); acc3 = fmaf(xa.w, wr3, acc3);
    }

    out[(base + row0 + 0) * FDIM + j] = fmaxf(acc0, 0.0f);
    out[(base + row0 + 1) * FDIM + j] = fmaxf(acc1, 0.0f);
    out[(base + row0 + 2) * FDIM + j] = fmaxf(acc2, 0.0f);
    out[(base + row0 + 3) * FDIM + j] = fmaxf(acc3, 0.0f);
}

// ---------------------------------------------------------------------------
extern "C" void kernel_launch(void* const* d_in, const int* in_sizes, int n_in,
                              void* d_out, int out_size, void* d_ws, size_t ws_size,
                              hipStream_t stream) {
    const float* x0  = (const float*)d_in[0];
    const int*   ei  = (const int*)d_in[1];
    const float* Wl0 = (const float*)d_in[2];
    const float* bl0 = (const float*)d_in[3];
    const float* Wr0 = (const float*)d_in[4];
    const float* Wl1 = (const float*)d_in[5];
    const float* bl1 = (const float*)d_in[6];
    const float* Wr1 = (const float*)d_in[7];
    float* out = (float*)d_out;

    const int* src = ei;            // edge_index[0]
    const int* dst = ei + N_EDGES;  // edge_index[1]

    // workspace: counts[N] | row_start[N+1] | cursor[N] | bsum[NB] | boff[NB] |
    //            csr_src[E] | m[N*64] | h1[N*64]
    int* counts    = (int*)d_ws;
    int* row_start = counts + N_NODES;
    int* cursor    = row_start + N_NODES + 1;
    int* bsum      = cursor + N_NODES;
    int* boff      = bsum + SCAN_NB;
    int* csr_src   = boff + SCAN_NB;
    float* mbuf    = (float*)(csr_src + N_EDGES);
    float* h1      = mbuf + (size_t)N_NODES * FDIM;

    hipMemsetAsync(counts, 0, N_NODES * sizeof(int), stream);
    count_kernel<<<(N_EDGES + 255) / 256, 256, 0, stream>>>(dst, counts);
    scan_reduce_kernel<<<SCAN_NB, 256, 0, stream>>>(counts, bsum);
    scan_sums_kernel<<<1, 256, 0, stream>>>(bsum, boff, row_start);
    scan_apply_kernel<<<SCAN_NB, 256, 0, stream>>>(counts, boff, row_start, cursor);
    fill_kernel<<<(N_EDGES + 255) / 256, 256, 0, stream>>>(src, dst, cursor, csr_src);

    const int tf_blocks = N_NODES / 16;   // 3125

    // ---- layer 0 ----
    gather_kernel<<<N_NODES / 4, 256, 0, stream>>>(x0, row_start, csr_src, mbuf);
    transform_kernel<<<tf_blocks, 256, 0, stream>>>(mbuf, x0, Wl0, bl0, Wr0, h1);

    // ---- layer 1 ----
    gather_kernel<<<N_NODES / 4, 256, 0, stream>>>(h1, row_start, csr_src, mbuf);
    transform_kernel<<<tf_blocks, 256, 0, stream>>>(mbuf, h1, Wl1, bl1, Wr1, out);
}

// Round 7
// 243.901 us; speedup vs baseline: 4.2632x; 1.2367x over previous
//
#include <hip/hip_runtime.h>
#include <hip/hip_bf16.h>

#define N_NODES 50000
#define N_EDGES 800000
#define FDIM 64
#define SCAN_NB ((N_NODES + 255) / 256)   // 196 blocks

typedef __attribute__((ext_vector_type(8))) short short8;
typedef __attribute__((ext_vector_type(4))) float f32x4;

// fp32 -> bf16 bits, round-to-nearest-even
__device__ __forceinline__ unsigned short f2bf(float f) {
    unsigned u = __float_as_uint(f);
    u += 0x7fffu + ((u >> 16) & 1u);
    return (unsigned short)(u >> 16);
}
// bf16 bits (in low 16 of u) -> fp32
__device__ __forceinline__ float bf2f_lo(unsigned u) { return __uint_as_float(u << 16); }
__device__ __forceinline__ float bf2f_hi(unsigned u) { return __uint_as_float(u & 0xffff0000u); }

// ---------------------------------------------------------------------------
// CSR build step 1: in-degree counts (int atomics)
// ---------------------------------------------------------------------------
__global__ void count_kernel(const int* __restrict__ dst, int* __restrict__ counts) {
    int e = blockIdx.x * blockDim.x + threadIdx.x;
    if (e < N_EDGES) atomicAdd(&counts[dst[e]], 1);
}

// ---------------------------------------------------------------------------
// CSR scan A: per-block sums of counts -> bsum
// ---------------------------------------------------------------------------
__global__ __launch_bounds__(256)
void scan_reduce_kernel(const int* __restrict__ counts, int* __restrict__ bsum) {
    __shared__ int wsum[4];
    int i = blockIdx.x * 256 + threadIdx.x;
    int v = (i < N_NODES) ? counts[i] : 0;
#pragma unroll
    for (int off = 32; off > 0; off >>= 1) v += __shfl_xor(v, off, 64);
    const int w = threadIdx.x >> 6;
    if ((threadIdx.x & 63) == 0) wsum[w] = v;
    __syncthreads();
    if (threadIdx.x == 0) bsum[blockIdx.x] = wsum[0] + wsum[1] + wsum[2] + wsum[3];
}

// ---------------------------------------------------------------------------
// CSR scan B: exclusive scan of bsum -> boff; total -> row_start[N]
// ---------------------------------------------------------------------------
__global__ __launch_bounds__(256)
void scan_sums_kernel(const int* __restrict__ bsum, int* __restrict__ boff,
                      int* __restrict__ row_start) {
    __shared__ int wtot[4];
    __shared__ int wincl[4];
    const int t = threadIdx.x;
    const int lane = t & 63;
    const int w = t >> 6;
    int v = (t < SCAN_NB) ? bsum[t] : 0;
    int sv = v;
#pragma unroll
    for (int off = 1; off < 64; off <<= 1) {
        int u = __shfl_up(sv, off, 64);
        if (lane >= off) sv += u;
    }
    if (lane == 63) wtot[w] = sv;
    __syncthreads();
    if (w == 0 && lane < 4) {
        int incl = 0;
#pragma unroll
        for (int k = 0; k < 4; ++k)
            if (k <= lane) incl += wtot[k];
        wincl[lane] = incl;
    }
    __syncthreads();
    int excl = (w ? wincl[w - 1] : 0) + sv - v;
    if (t < SCAN_NB) boff[t] = excl;
    if (t == SCAN_NB - 1) row_start[N_NODES] = excl + v;
}

// ---------------------------------------------------------------------------
// CSR scan C: apply — row_start[i] = cursor[i] = boff[b] + in-block excl scan
// ---------------------------------------------------------------------------
__global__ __launch_bounds__(256)
void scan_apply_kernel(const int* __restrict__ counts, const int* __restrict__ boff,
                       int* __restrict__ row_start, int* __restrict__ cursor) {
    __shared__ int wtot[4];
    __shared__ int wincl[4];
    const int t = threadIdx.x;
    const int lane = t & 63;
    const int w = t >> 6;
    int i = blockIdx.x * 256 + t;
    int v = (i < N_NODES) ? counts[i] : 0;
    int sv = v;
#pragma unroll
    for (int off = 1; off < 64; off <<= 1) {
        int u = __shfl_up(sv, off, 64);
        if (lane >= off) sv += u;
    }
    if (lane == 63) wtot[w] = sv;
    __syncthreads();
    if (w == 0 && lane < 4) {
        int incl = 0;
#pragma unroll
        for (int k = 0; k < 4; ++k)
            if (k <= lane) incl += wtot[k];
        wincl[lane] = incl;
    }
    __syncthreads();
    int excl = (w ? wincl[w - 1] : 0) + sv - v;
    int val = boff[blockIdx.x] + excl;
    if (i < N_NODES) { row_start[i] = val; cursor[i] = val; }
}

// ---------------------------------------------------------------------------
// CSR fill: bucket sources by destination (plain store — NT regressed)
// ---------------------------------------------------------------------------
__global__ void fill_kernel(const int* __restrict__ src, const int* __restrict__ dst,
                            int* __restrict__ cursor, int* __restrict__ csr_src) {
    int e = blockIdx.x * blockDim.x + threadIdx.x;
    if (e < N_EDGES) {
        int d = dst[e];
        int pos = atomicAdd(&cursor[d], 1);
        csr_src[pos] = src[e];
    }
}

// ---------------------------------------------------------------------------
// fp32 -> bf16 conversion of x0 (3.2M elems; 4/thread)
// ---------------------------------------------------------------------------
__global__ __launch_bounds__(256)
void convert_bf_kernel(const float* __restrict__ in, unsigned short* __restrict__ out) {
    int i = (blockIdx.x * 256 + threadIdx.x) * 4;   // grid 3125 -> exactly 3.2M
    float4 v = *(const float4*)(in + i);
    uint2 o;
    o.x = (unsigned)f2bf(v.x) | ((unsigned)f2bf(v.y) << 16);
    o.y = (unsigned)f2bf(v.z) | ((unsigned)f2bf(v.w) << 16);
    *(uint2*)(out + i) = o;
}

// ---------------------------------------------------------------------------
// pack weights into MFMA B-fragment order (bf16):
// P[((ct*2+kk)*64 + lane)*8 + j] = W[k][col], k = kk*32 + ((lane>>4)&3)*8 + j,
// col = ct*16 + (lane&15).  4 blocks, one per matrix.
// ---------------------------------------------------------------------------
__global__ __launch_bounds__(256)
void pack_weights_kernel(const float* __restrict__ Wl0, const float* __restrict__ Wr0,
                         const float* __restrict__ Wl1, const float* __restrict__ Wr1,
                         unsigned short* __restrict__ pWl0, unsigned short* __restrict__ pWr0,
                         unsigned short* __restrict__ pWl1, unsigned short* __restrict__ pWr1) {
    const float* srcs[4] = {Wl0, Wr0, Wl1, Wr1};
    unsigned short* dsts[4] = {pWl0, pWr0, pWl1, pWr1};
    const float* W = srcs[blockIdx.x];
    unsigned short* P = dsts[blockIdx.x];
    for (int idx = threadIdx.x; idx < FDIM * FDIM; idx += 256) {
        int j = idx & 7;
        int lane = (idx >> 3) & 63;
        int g = idx >> 9;              // ct*2 + kk, 0..7
        int ct = g >> 1, kk = g & 1;
        int k = kk * 32 + ((lane >> 4) & 3) * 8 + j;
        int col = ct * 16 + (lane & 15);
        P[idx] = f2bf(W[k * FDIM + col]);
    }
}

// ---------------------------------------------------------------------------
// gather (bf16): one wave per node. lane = q(0..7 edge slot) x c(0..7 col-oct).
// Row read = 8 lanes x 16B = 128B. 8 slots x2 unroll = 16 rows in flight.
// m_bf[n][:] = bf16( (x[n][:] + sum_neighbors) / (deg+1) )
// ---------------------------------------------------------------------------
__global__ __launch_bounds__(256)
void gather_bf_kernel(const unsigned short* __restrict__ xb,
                      const int* __restrict__ row_start,
                      const int* __restrict__ csr_src,
                      unsigned short* __restrict__ mb) {
    const int w = threadIdx.x >> 6;
    const int lane = threadIdx.x & 63;
    const int q = lane >> 3;          // edge slot 0..7
    const int c = lane & 7;           // cols 8c..8c+7
    const int n = blockIdx.x * 4 + w; // grid = 12500*4 = 50000 exactly

    const int rs = row_start[n];
    const int re = row_start[n + 1];

    float s0 = 0.f, s1 = 0.f, s2 = 0.f, s3 = 0.f, s4 = 0.f, s5 = 0.f, s6 = 0.f, s7 = 0.f;

#define ADDROW(node) do {                                              \
        uint4 v_ = *(const uint4*)(xb + (size_t)(node) * FDIM + c * 8);\
        s0 += bf2f_lo(v_.x); s1 += bf2f_hi(v_.x);                      \
        s2 += bf2f_lo(v_.y); s3 += bf2f_hi(v_.y);                      \
        s4 += bf2f_lo(v_.z); s5 += bf2f_hi(v_.z);                      \
        s6 += bf2f_lo(v_.w); s7 += bf2f_hi(v_.w);                      \
    } while (0)

    if (q == 0) ADDROW(n);            // self-loop

    int idx = rs + q;
    for (; idx + 8 < re; idx += 16) {
        int a = csr_src[idx];
        int b = csr_src[idx + 8];
        ADDROW(a);
        ADDROW(b);
    }
    for (; idx < re; idx += 8) ADDROW(csr_src[idx]);
#undef ADDROW

#pragma unroll
    for (int off = 8; off < 64; off <<= 1) {
        s0 += __shfl_xor(s0, off, 64);
        s1 += __shfl_xor(s1, off, 64);
        s2 += __shfl_xor(s2, off, 64);
        s3 += __shfl_xor(s3, off, 64);
        s4 += __shfl_xor(s4, off, 64);
        s5 += __shfl_xor(s5, off, 64);
        s6 += __shfl_xor(s6, off, 64);
        s7 += __shfl_xor(s7, off, 64);
    }

    if (q == 0) {
        float inv = 1.0f / (float)(re - rs + 1);
        uint4 o;
        o.x = (unsigned)f2bf(s0 * inv) | ((unsigned)f2bf(s1 * inv) << 16);
        o.y = (unsigned)f2bf(s2 * inv) | ((unsigned)f2bf(s3 * inv) << 16);
        o.z = (unsigned)f2bf(s4 * inv) | ((unsigned)f2bf(s5 * inv) << 16);
        o.w = (unsigned)f2bf(s6 * inv) | ((unsigned)f2bf(s7 * inv) << 16);
        *(uint4*)(mb + (size_t)n * FDIM + c * 8) = o;
    }
}

// ---------------------------------------------------------------------------
// MFMA transform: out = relu( m @ Wl + bl + x @ Wr )
// block 256 = 4 waves; wave ct computes 16 nodes x cols[ct*16..ct*16+15].
// A layout: A[m=lane&15][k=(lane>>4)*8+j]; C/D: col=lane&15, row=(lane>>4)*4+reg.
// No LDS, no syncthreads. Grid = 3125 (x16 nodes = 50000 exactly).
// ---------------------------------------------------------------------------
template <bool OUT_BF16>
__global__ __launch_bounds__(256)
void transform_mfma_kernel(const unsigned short* __restrict__ mb,
                           const unsigned short* __restrict__ xb,
                           const unsigned short* __restrict__ pWl,
                           const float* __restrict__ bl,
                           const unsigned short* __restrict__ pWr,
                           float* __restrict__ out_f32,
                           unsigned short* __restrict__ out_bf) {
    const int ct = threadIdx.x >> 6;   // col-tile 0..3
    const int lane = threadIdx.x & 63;
    const int q = lane >> 4;
    const int r = lane & 15;
    const int base = blockIdx.x * 16;

    const size_t arow = (size_t)(base + r) * FDIM;
    short8 am0 = *(const short8*)(mb + arow + q * 8);        // k 0..31
    short8 am1 = *(const short8*)(mb + arow + 32 + q * 8);   // k 32..63
    short8 ax0 = *(const short8*)(xb + arow + q * 8);
    short8 ax1 = *(const short8*)(xb + arow + 32 + q * 8);

    const short8* pl = (const short8*)pWl;
    const short8* pr = (const short8*)pWr;
    short8 bl0v = pl[(ct * 2 + 0) * 64 + lane];
    short8 bl1v = pl[(ct * 2 + 1) * 64 + lane];
    short8 br0v = pr[(ct * 2 + 0) * 64 + lane];
    short8 br1v = pr[(ct * 2 + 1) * 64 + lane];

    float b = bl[ct * 16 + r];
    f32x4 acc = {b, b, b, b};
    acc = __builtin_amdgcn_mfma_f32_16x16x32_bf16(am0, bl0v, acc, 0, 0, 0);
    acc = __builtin_amdgcn_mfma_f32_16x16x32_bf16(am1, bl1v, acc, 0, 0, 0);
    acc = __builtin_amdgcn_mfma_f32_16x16x32_bf16(ax0, br0v, acc, 0, 0, 0);
    acc = __builtin_amdgcn_mfma_f32_16x16x32_bf16(ax1, br1v, acc, 0, 0, 0);

#pragma unroll
    for (int reg = 0; reg < 4; ++reg) {
        int node = base + q * 4 + reg;
        float v = fmaxf(acc[reg], 0.0f);
        if (OUT_BF16) out_bf[(size_t)node * FDIM + ct * 16 + r] = f2bf(v);
        else          out_f32[(size_t)node * FDIM + ct * 16 + r] = v;
    }
}

// ---------------------------------------------------------------------------
extern "C" void kernel_launch(void* const* d_in, const int* in_sizes, int n_in,
                              void* d_out, int out_size, void* d_ws, size_t ws_size,
                              hipStream_t stream) {
    const float* x0  = (const float*)d_in[0];
    const int*   ei  = (const int*)d_in[1];
    const float* Wl0 = (const float*)d_in[2];
    const float* bl0 = (const float*)d_in[3];
    const float* Wr0 = (const float*)d_in[4];
    const float* Wl1 = (const float*)d_in[5];
    const float* bl1 = (const float*)d_in[6];
    const float* Wr1 = (const float*)d_in[7];
    float* out = (float*)d_out;

    const int* src = ei;            // edge_index[0]
    const int* dst = ei + N_EDGES;  // edge_index[1]

    // int region (padded for 16B alignment of what follows)
    int* counts    = (int*)d_ws;                 // 50000
    int* row_start = counts + 50000;             // 50004 (padded)
    int* cursor    = row_start + 50004;          // 50000
    int* bsum      = cursor + 50000;             // 200
    int* boff      = bsum + 200;                 // 200
    int* csr_src   = boff + 200;                 // 800000
    // bf16 (ushort) region — starts 16B-aligned
    unsigned short* x_bf = (unsigned short*)(csr_src + N_EDGES);  // 3.2M
    unsigned short* m_bf = x_bf + (size_t)N_NODES * FDIM;         // 3.2M
    unsigned short* h_bf = m_bf + (size_t)N_NODES * FDIM;         // 3.2M
    unsigned short* pWl0p = h_bf + (size_t)N_NODES * FDIM;        // 4096
    unsigned short* pWr0p = pWl0p + FDIM * FDIM;
    unsigned short* pWl1p = pWr0p + FDIM * FDIM;
    unsigned short* pWr1p = pWl1p + FDIM * FDIM;

    hipMemsetAsync(counts, 0, N_NODES * sizeof(int), stream);
    count_kernel<<<(N_EDGES + 255) / 256, 256, 0, stream>>>(dst, counts);
    scan_reduce_kernel<<<SCAN_NB, 256, 0, stream>>>(counts, bsum);
    scan_sums_kernel<<<1, 256, 0, stream>>>(bsum, boff, row_start);
    scan_apply_kernel<<<SCAN_NB, 256, 0, stream>>>(counts, boff, row_start, cursor);
    fill_kernel<<<(N_EDGES + 255) / 256, 256, 0, stream>>>(src, dst, cursor, csr_src);

    convert_bf_kernel<<<(N_NODES * FDIM) / 1024, 256, 0, stream>>>(x0, x_bf);
    pack_weights_kernel<<<4, 256, 0, stream>>>(Wl0, Wr0, Wl1, Wr1,
                                               pWl0p, pWr0p, pWl1p, pWr1p);

    // ---- layer 0 ----
    gather_bf_kernel<<<N_NODES / 4, 256, 0, stream>>>(x_bf, row_start, csr_src, m_bf);
    transform_mfma_kernel<true><<<N_NODES / 16, 256, 0, stream>>>(
        m_bf, x_bf, pWl0p, bl0, pWr0p, nullptr, h_bf);

    // ---- layer 1 ----
    gather_bf_kernel<<<N_NODES / 4, 256, 0, stream>>>(h_bf, row_start, csr_src, m_bf);
    transform_mfma_kernel<false><<<N_NODES / 16, 256, 0, stream>>>(
        m_bf, h_bf, pWl1p, bl1, pWr1p, out, nullptr);
}

// Round 8
// 225.866 us; speedup vs baseline: 4.6036x; 1.0798x over previous
//
#include <hip/hip_runtime.h>
#include <hip/hip_bf16.h>

#define N_NODES 50000
#define N_EDGES 800000
#define FDIM 64
#define SCAN_NB ((N_NODES + 255) / 256)   // 196 blocks

typedef __attribute__((ext_vector_type(8))) short short8;
typedef __attribute__((ext_vector_type(4))) float f32x4;

// fp32 -> bf16 bits, round-to-nearest-even
__device__ __forceinline__ unsigned short f2bf(float f) {
    unsigned u = __float_as_uint(f);
    u += 0x7fffu + ((u >> 16) & 1u);
    return (unsigned short)(u >> 16);
}
// bf16 bits -> fp32
__device__ __forceinline__ float bf2f_lo(unsigned u) { return __uint_as_float(u << 16); }
__device__ __forceinline__ float bf2f_hi(unsigned u) { return __uint_as_float(u & 0xffff0000u); }

// ---------------------------------------------------------------------------
// preprocess (fused): blocks [0,3124] convert x0->bf16; [3125,3128] pack W;
// [3129,3177] zero counts.  All independent of the CSR chain.
// ---------------------------------------------------------------------------
__global__ __launch_bounds__(256)
void preprocess_kernel(const float* __restrict__ x0, unsigned short* __restrict__ x_bf,
                       const float* __restrict__ Wl0, const float* __restrict__ Wr0,
                       const float* __restrict__ Wl1, const float* __restrict__ Wr1,
                       unsigned short* __restrict__ pWl0, unsigned short* __restrict__ pWr0,
                       unsigned short* __restrict__ pWl1, unsigned short* __restrict__ pWr1,
                       int* __restrict__ counts) {
    const int b = blockIdx.x;
    if (b < 3125) {                       // convert: 3125*256*4 = 3.2M exactly
        int i = (b * 256 + threadIdx.x) * 4;
        float4 v = *(const float4*)(x0 + i);
        uint2 o;
        o.x = (unsigned)f2bf(v.x) | ((unsigned)f2bf(v.y) << 16);
        o.y = (unsigned)f2bf(v.z) | ((unsigned)f2bf(v.w) << 16);
        *(uint2*)(x_bf + i) = o;
    } else if (b < 3129) {                // pack weights into B-fragment order
        const float* srcs[4] = {Wl0, Wr0, Wl1, Wr1};
        unsigned short* dsts[4] = {pWl0, pWr0, pWl1, pWr1};
        const float* W = srcs[b - 3125];
        unsigned short* P = dsts[b - 3125];
        for (int idx = threadIdx.x; idx < FDIM * FDIM; idx += 256) {
            int j = idx & 7;
            int lane = (idx >> 3) & 63;
            int g = idx >> 9;             // ct*2 + kk
            int ct = g >> 1, kk = g & 1;
            int k = kk * 32 + ((lane >> 4) & 3) * 8 + j;
            int col = ct * 16 + (lane & 15);
            P[idx] = f2bf(W[k * FDIM + col]);
        }
    } else {                              // zero counts: 49 blocks * 1024 ints
        int i = ((b - 3129) * 256 + threadIdx.x) * 4;
        if (i < N_NODES) *(int4*)(counts + i) = make_int4(0, 0, 0, 0);
    }
}

// ---------------------------------------------------------------------------
// CSR build step 1: in-degree counts (int atomics)
// ---------------------------------------------------------------------------
__global__ void count_kernel(const int* __restrict__ dst, int* __restrict__ counts) {
    int e = blockIdx.x * blockDim.x + threadIdx.x;
    if (e < N_EDGES) atomicAdd(&counts[dst[e]], 1);
}

// ---------------------------------------------------------------------------
// CSR scan A: per-block sums of counts -> bsum[196]
// ---------------------------------------------------------------------------
__global__ __launch_bounds__(256)
void scan_reduce_kernel(const int* __restrict__ counts, int* __restrict__ bsum) {
    __shared__ int wsum[4];
    int i = blockIdx.x * 256 + threadIdx.x;
    int v = (i < N_NODES) ? counts[i] : 0;
#pragma unroll
    for (int off = 32; off > 0; off >>= 1) v += __shfl_xor(v, off, 64);
    const int w = threadIdx.x >> 6;
    if ((threadIdx.x & 63) == 0) wsum[w] = v;
    __syncthreads();
    if (threadIdx.x == 0) bsum[blockIdx.x] = wsum[0] + wsum[1] + wsum[2] + wsum[3];
}

// ---------------------------------------------------------------------------
// CSR scan B (fused): every block scans bsum[196] redundantly for its offset,
// then does its in-block exclusive scan of counts -> row_start / cursor.
// row_start[N] = N_EDGES is a compile-time constant (written by block 0).
// ---------------------------------------------------------------------------
__global__ __launch_bounds__(256)
void scan_apply_kernel(const int* __restrict__ counts, const int* __restrict__ bsum,
                       int* __restrict__ row_start, int* __restrict__ cursor) {
    __shared__ int sEx[256];
    __shared__ int wtot[4];
    __shared__ int wincl[4];
    const int t = threadIdx.x;
    const int lane = t & 63;
    const int w = t >> 6;

    // --- exclusive scan of bsum across 196 blocks (all threads) ---
    int v = (t < SCAN_NB) ? bsum[t] : 0;
    int sv = v;
#pragma unroll
    for (int off = 1; off < 64; off <<= 1) {
        int u = __shfl_up(sv, off, 64);
        if (lane >= off) sv += u;
    }
    if (lane == 63) wtot[w] = sv;
    __syncthreads();
    if (w == 0 && lane < 4) {
        int incl = 0;
#pragma unroll
        for (int k = 0; k < 4; ++k)
            if (k <= lane) incl += wtot[k];
        wincl[lane] = incl;
    }
    __syncthreads();
    sEx[t] = (w ? wincl[w - 1] : 0) + sv - v;
    __syncthreads();
    const int boff_v = sEx[blockIdx.x];
    if (blockIdx.x == 0 && t == 0) row_start[N_NODES] = N_EDGES;
    __syncthreads();   // done reading wtot/wincl before reuse

    // --- in-block scan of counts ---
    int i = blockIdx.x * 256 + t;
    int c = (i < N_NODES) ? counts[i] : 0;
    int sc = c;
#pragma unroll
    for (int off = 1; off < 64; off <<= 1) {
        int u = __shfl_up(sc, off, 64);
        if (lane >= off) sc += u;
    }
    if (lane == 63) wtot[w] = sc;
    __syncthreads();
    if (w == 0 && lane < 4) {
        int incl = 0;
#pragma unroll
        for (int k = 0; k < 4; ++k)
            if (k <= lane) incl += wtot[k];
        wincl[lane] = incl;
    }
    __syncthreads();
    int ex = (w ? wincl[w - 1] : 0) + sc - c;
    int val = boff_v + ex;
    if (i < N_NODES) { row_start[i] = val; cursor[i] = val; }
}

// ---------------------------------------------------------------------------
// CSR fill: bucket sources by destination. csr is uint16 (N_NODES < 65536)
// -> halves the scattered-store footprint vs int32.
// ---------------------------------------------------------------------------
__global__ void fill_kernel(const int* __restrict__ src, const int* __restrict__ dst,
                            int* __restrict__ cursor, unsigned short* __restrict__ csr) {
    int e = blockIdx.x * blockDim.x + threadIdx.x;
    if (e < N_EDGES) {
        int d = dst[e];
        int pos = atomicAdd(&cursor[d], 1);
        csr[pos] = (unsigned short)src[e];
    }
}

// ---------------------------------------------------------------------------
// gather (bf16): one wave per node. lane = q(0..7 edge slot) x c(0..7 col-oct).
// Row read = 8 lanes x 16B = 128B; 8 slots x2 unroll = 16 rows in flight.
// ---------------------------------------------------------------------------
__global__ __launch_bounds__(256)
void gather_bf_kernel(const unsigned short* __restrict__ xb,
                      const int* __restrict__ row_start,
                      const unsigned short* __restrict__ csr,
                      unsigned short* __restrict__ mb) {
    const int w = threadIdx.x >> 6;
    const int lane = threadIdx.x & 63;
    const int q = lane >> 3;          // edge slot 0..7
    const int c = lane & 7;           // cols 8c..8c+7
    const int n = blockIdx.x * 4 + w; // grid = 12500*4 = 50000 exactly

    const int rs = row_start[n];
    const int re = row_start[n + 1];

    float s0 = 0.f, s1 = 0.f, s2 = 0.f, s3 = 0.f, s4 = 0.f, s5 = 0.f, s6 = 0.f, s7 = 0.f;

#define ADDROW(node) do {                                              \
        uint4 v_ = *(const uint4*)(xb + (size_t)(node) * FDIM + c * 8);\
        s0 += bf2f_lo(v_.x); s1 += bf2f_hi(v_.x);                      \
        s2 += bf2f_lo(v_.y); s3 += bf2f_hi(v_.y);                      \
        s4 += bf2f_lo(v_.z); s5 += bf2f_hi(v_.z);                      \
        s6 += bf2f_lo(v_.w); s7 += bf2f_hi(v_.w);                      \
    } while (0)

    if (q == 0) ADDROW(n);            // self-loop

    int idx = rs + q;
    for (; idx + 8 < re; idx += 16) {
        int a = csr[idx];
        int b = csr[idx + 8];
        ADDROW(a);
        ADDROW(b);
    }
    for (; idx < re; idx += 8) ADDROW((int)csr[idx]);
#undef ADDROW

#pragma unroll
    for (int off = 8; off < 64; off <<= 1) {
        s0 += __shfl_xor(s0, off, 64);
        s1 += __shfl_xor(s1, off, 64);
        s2 += __shfl_xor(s2, off, 64);
        s3 += __shfl_xor(s3, off, 64);
        s4 += __shfl_xor(s4, off, 64);
        s5 += __shfl_xor(s5, off, 64);
        s6 += __shfl_xor(s6, off, 64);
        s7 += __shfl_xor(s7, off, 64);
    }

    if (q == 0) {
        float inv = 1.0f / (float)(re - rs + 1);
        uint4 o;
        o.x = (unsigned)f2bf(s0 * inv) | ((unsigned)f2bf(s1 * inv) << 16);
        o.y = (unsigned)f2bf(s2 * inv) | ((unsigned)f2bf(s3 * inv) << 16);
        o.z = (unsigned)f2bf(s4 * inv) | ((unsigned)f2bf(s5 * inv) << 16);
        o.w = (unsigned)f2bf(s6 * inv) | ((unsigned)f2bf(s7 * inv) << 16);
        *(uint4*)(mb + (size_t)n * FDIM + c * 8) = o;
    }
}

// ---------------------------------------------------------------------------
// MFMA transform: out = relu( m @ Wl + bl + x @ Wr )
// block 256 = 4 waves; wave ct computes 16 nodes x cols[ct*16..ct*16+15].
// A layout: A[m=lane&15][k=(lane>>4)*8+j]; C/D: col=lane&15, row=(lane>>4)*4+reg.
// ---------------------------------------------------------------------------
template <bool OUT_BF16>
__global__ __launch_bounds__(256)
void transform_mfma_kernel(const unsigned short* __restrict__ mb,
                           const unsigned short* __restrict__ xb,
                           const unsigned short* __restrict__ pWl,
                           const float* __restrict__ bl,
                           const unsigned short* __restrict__ pWr,
                           float* __restrict__ out_f32,
                           unsigned short* __restrict__ out_bf) {
    const int ct = threadIdx.x >> 6;   // col-tile 0..3
    const int lane = threadIdx.x & 63;
    const int q = lane >> 4;
    const int r = lane & 15;
    const int base = blockIdx.x * 16;

    const size_t arow = (size_t)(base + r) * FDIM;
    short8 am0 = *(const short8*)(mb + arow + q * 8);
    short8 am1 = *(const short8*)(mb + arow + 32 + q * 8);
    short8 ax0 = *(const short8*)(xb + arow + q * 8);
    short8 ax1 = *(const short8*)(xb + arow + 32 + q * 8);

    const short8* pl = (const short8*)pWl;
    const short8* pr = (const short8*)pWr;
    short8 bl0v = pl[(ct * 2 + 0) * 64 + lane];
    short8 bl1v = pl[(ct * 2 + 1) * 64 + lane];
    short8 br0v = pr[(ct * 2 + 0) * 64 + lane];
    short8 br1v = pr[(ct * 2 + 1) * 64 + lane];

    float b = bl[ct * 16 + r];
    f32x4 acc = {b, b, b, b};
    acc = __builtin_amdgcn_mfma_f32_16x16x32_bf16(am0, bl0v, acc, 0, 0, 0);
    acc = __builtin_amdgcn_mfma_f32_16x16x32_bf16(am1, bl1v, acc, 0, 0, 0);
    acc = __builtin_amdgcn_mfma_f32_16x16x32_bf16(ax0, br0v, acc, 0, 0, 0);
    acc = __builtin_amdgcn_mfma_f32_16x16x32_bf16(ax1, br1v, acc, 0, 0, 0);

#pragma unroll
    for (int reg = 0; reg < 4; ++reg) {
        int node = base + q * 4 + reg;
        float v = fmaxf(acc[reg], 0.0f);
        if (OUT_BF16) out_bf[(size_t)node * FDIM + ct * 16 + r] = f2bf(v);
        else          out_f32[(size_t)node * FDIM + ct * 16 + r] = v;
    }
}

// ---------------------------------------------------------------------------
extern "C" void kernel_launch(void* const* d_in, const int* in_sizes, int n_in,
                              void* d_out, int out_size, void* d_ws, size_t ws_size,
                              hipStream_t stream) {
    const float* x0  = (const float*)d_in[0];
    const int*   ei  = (const int*)d_in[1];
    const float* Wl0 = (const float*)d_in[2];
    const float* bl0 = (const float*)d_in[3];
    const float* Wr0 = (const float*)d_in[4];
    const float* Wl1 = (const float*)d_in[5];
    const float* bl1 = (const float*)d_in[6];
    const float* Wr1 = (const float*)d_in[7];
    float* out = (float*)d_out;

    const int* src = ei;            // edge_index[0]
    const int* dst = ei + N_EDGES;  // edge_index[1]

    // workspace (ints): counts[50000] | row_start[50004] | cursor[50000] | bsum[204]
    // then 16B-aligned: csr_u16[800000] | x_bf | m_bf | h_bf | packed weights
    int* counts    = (int*)d_ws;
    int* row_start = counts + 50000;
    int* cursor    = row_start + 50004;
    int* bsum      = cursor + 50000;
    unsigned short* csr_u16 = (unsigned short*)(bsum + 204);
    unsigned short* x_bf = csr_u16 + N_EDGES;
    unsigned short* m_bf = x_bf + (size_t)N_NODES * FDIM;
    unsigned short* h_bf = m_bf + (size_t)N_NODES * FDIM;
    unsigned short* pWl0p = h_bf + (size_t)N_NODES * FDIM;
    unsigned short* pWr0p = pWl0p + FDIM * FDIM;
    unsigned short* pWl1p = pWr0p + FDIM * FDIM;
    unsigned short* pWr1p = pWl1p + FDIM * FDIM;

    preprocess_kernel<<<3178, 256, 0, stream>>>(x0, x_bf, Wl0, Wr0, Wl1, Wr1,
                                                pWl0p, pWr0p, pWl1p, pWr1p, counts);
    count_kernel<<<(N_EDGES + 255) / 256, 256, 0, stream>>>(dst, counts);
    scan_reduce_kernel<<<SCAN_NB, 256, 0, stream>>>(counts, bsum);
    scan_apply_kernel<<<SCAN_NB, 256, 0, stream>>>(counts, bsum, row_start, cursor);
    fill_kernel<<<(N_EDGES + 255) / 256, 256, 0, stream>>>(src, dst, cursor, csr_u16);

    // ---- layer 0 ----
    gather_bf_kernel<<<N_NODES / 4, 256, 0, stream>>>(x_bf, row_start, csr_u16, m_bf);
    transform_mfma_kernel<true><<<N_NODES / 16, 256, 0, stream>>>(
        m_bf, x_bf, pWl0p, bl0, pWr0p, nullptr, h_bf);

    // ---- layer 1 ----
    gather_bf_kernel<<<N_NODES / 4, 256, 0, stream>>>(h_bf, row_start, csr_u16, m_bf);
    transform_mfma_kernel<false><<<N_NODES / 16, 256, 0, stream>>>(
        m_bf, h_bf, pWl1p, bl1, pWr1p, out, nullptr);
}

// Round 9
// 199.304 us; speedup vs baseline: 5.2172x; 1.1333x over previous
//
#include <hip/hip_runtime.h>
#include <hip/hip_bf16.h>

#define N_NODES 50000
#define N_EDGES 800000
#define FDIM 64
#define NBUCK 196          // ceil(50000/256) buckets of 256 nodes
#define PAD 16             // one counter per 64B line

typedef __attribute__((ext_vector_type(8))) short short8;
typedef __attribute__((ext_vector_type(4))) float f32x4;

// fp32 -> bf16 bits, round-to-nearest-even
__device__ __forceinline__ unsigned short f2bf(float f) {
    unsigned u = __float_as_uint(f);
    u += 0x7fffu + ((u >> 16) & 1u);
    return (unsigned short)(u >> 16);
}
__device__ __forceinline__ float bf2f_lo(unsigned u) { return __uint_as_float(u << 16); }
__device__ __forceinline__ float bf2f_hi(unsigned u) { return __uint_as_float(u & 0xffff0000u); }

// exclusive scan of one value per thread across a 256-thread block.
// Safe to call repeatedly (wtot/wincl reuse is sync-protected).
__device__ __forceinline__ int excl_scan_256(int v, int* wtot, int* wincl) {
    const int t = threadIdx.x, lane = t & 63, w = t >> 6;
    int sv = v;
#pragma unroll
    for (int off = 1; off < 64; off <<= 1) {
        int u = __shfl_up(sv, off, 64);
        if (lane >= off) sv += u;
    }
    if (lane == 63) wtot[w] = sv;
    __syncthreads();
    if (w == 0 && lane < 4) {
        int incl = 0;
#pragma unroll
        for (int k = 0; k < 4; ++k)
            if (k <= lane) incl += wtot[k];
        wincl[lane] = incl;
    }
    __syncthreads();
    return (w ? wincl[w - 1] : 0) + sv - v;
}

// ---------------------------------------------------------------------------
// preprocess (fused): [0,3124] convert x0->bf16; [3125,3128] pack weights;
// [3129,3910] bucket histogram of dst>>8 (LDS-aggregated, padded counters).
// ---------------------------------------------------------------------------
__global__ __launch_bounds__(256)
void preprocess_kernel(const float* __restrict__ x0, unsigned short* __restrict__ x_bf,
                       const float* __restrict__ Wl0, const float* __restrict__ Wr0,
                       const float* __restrict__ Wl1, const float* __restrict__ Wr1,
                       unsigned short* __restrict__ pWl0, unsigned short* __restrict__ pWr0,
                       unsigned short* __restrict__ pWl1, unsigned short* __restrict__ pWr1,
                       const int* __restrict__ dst, int* __restrict__ bc_pad) {
    const int b = blockIdx.x;
    if (b < 3125) {                       // convert: 3125*256*4 = 3.2M exactly
        int i = (b * 256 + threadIdx.x) * 4;
        float4 v = *(const float4*)(x0 + i);
        uint2 o;
        o.x = (unsigned)f2bf(v.x) | ((unsigned)f2bf(v.y) << 16);
        o.y = (unsigned)f2bf(v.z) | ((unsigned)f2bf(v.w) << 16);
        *(uint2*)(x_bf + i) = o;
    } else if (b < 3129) {                // pack weights into B-fragment order
        const float* srcs[4] = {Wl0, Wr0, Wl1, Wr1};
        unsigned short* dsts[4] = {pWl0, pWr0, pWl1, pWr1};
        const float* W = srcs[b - 3125];
        unsigned short* P = dsts[b - 3125];
        for (int idx = threadIdx.x; idx < FDIM * FDIM; idx += 256) {
            int j = idx & 7;
            int lane = (idx >> 3) & 63;
            int g = idx >> 9;
            int ct = g >> 1, kk = g & 1;
            int k = kk * 32 + ((lane >> 4) & 3) * 8 + j;
            int col = ct * 16 + (lane & 15);
            P[idx] = f2bf(W[k * FDIM + col]);
        }
    } else {                              // bucket histogram: 782 blocks x 1024 edges
        __shared__ int h[NBUCK];
        if (threadIdx.x < NBUCK) h[threadIdx.x] = 0;
        __syncthreads();
        int e0 = (b - 3129) * 1024;
#pragma unroll
        for (int k = 0; k < 4; ++k) {
            int e = e0 + k * 256 + threadIdx.x;
            if (e < N_EDGES) atomicAdd(&h[dst[e] >> 8], 1);
        }
        __syncthreads();
        if (threadIdx.x < NBUCK) {
            int c = h[threadIdx.x];
            if (c) atomicAdd(&bc_pad[threadIdx.x * PAD], c);
        }
    }
}

// ---------------------------------------------------------------------------
// bucket scatter: rank edges per bucket in LDS, reserve space with one padded
// global atomic per (block,bucket), write packed (dst<<16)|src to ebuf.
// Writes advance ~196 sequential line-frontiers -> low write amplification.
// ---------------------------------------------------------------------------
__global__ __launch_bounds__(256)
void bucket_scatter_kernel(const int* __restrict__ src, const int* __restrict__ dst,
                           const int* __restrict__ bc_pad, int* __restrict__ cur_pad,
                           unsigned* __restrict__ ebuf) {
    __shared__ int h[NBUCK];
    __shared__ int base[NBUCK];
    __shared__ int sEx[256];
    __shared__ int wtot[4], wincl[4];
    const int t = threadIdx.x;

    // redundant exclusive scan of bucket counts -> bucket offsets
    int v = (t < NBUCK) ? bc_pad[t * PAD] : 0;
    sEx[t] = excl_scan_256(v, wtot, wincl);
    if (t < NBUCK) h[t] = 0;
    __syncthreads();

    int e0 = blockIdx.x * 1024;
    int bk[4], rk[4]; unsigned pk[4];
#pragma unroll
    for (int k = 0; k < 4; ++k) {
        int e = e0 + k * 256 + t;
        if (e < N_EDGES) {
            int d = dst[e];
            bk[k] = d >> 8;
            pk[k] = ((unsigned)d << 16) | (unsigned)src[e];
            rk[k] = atomicAdd(&h[bk[k]], 1);
        } else bk[k] = -1;
    }
    __syncthreads();
    if (t < NBUCK) {
        int c = h[t];
        base[t] = c ? (sEx[t] + atomicAdd(&cur_pad[t * PAD], c)) : 0;
    }
    __syncthreads();
#pragma unroll
    for (int k = 0; k < 4; ++k)
        if (bk[k] >= 0) ebuf[base[bk[k]] + rk[k]] = pk[k];
}

// ---------------------------------------------------------------------------
// bucket CSR finalize: one block per bucket (256 nodes). LDS histogram of
// dst&255 -> LDS scan -> row_start; LDS-cursor scatter of csr (u16 src)
// confined to the bucket's contiguous ~8KB window. Replaces count+scan+fill.
// ---------------------------------------------------------------------------
__global__ __launch_bounds__(256)
void bucket_csr_kernel(const unsigned* __restrict__ ebuf, const int* __restrict__ bc_pad,
                       int* __restrict__ row_start, unsigned short* __restrict__ csr) {
    __shared__ int sEx[257];
    __shared__ int cnt[256];
    __shared__ int cur[256];
    __shared__ int wtot[4], wincl[4];
    const int t = threadIdx.x;

    // redundant exclusive scan of bucket counts -> this bucket's [s, e)
    int v = (t < NBUCK) ? bc_pad[t * PAD] : 0;
    sEx[t] = excl_scan_256(v, wtot, wincl);
    if (t == 255) sEx[256] = sEx[255];            // bucket 255 unused (NBUCK=196)
    cnt[t] = 0;
    __syncthreads();
    const int s = sEx[blockIdx.x];
    const int e = sEx[blockIdx.x + 1];

    // local histogram of dst&255
    for (int i = s + t; i < e; i += 256)
        atomicAdd(&cnt[(ebuf[i] >> 16) & 255], 1);
    __syncthreads();

    // local exclusive scan -> row_start + cursors
    int c = cnt[t];
    int ex = excl_scan_256(c, wtot, wincl);
    cur[t] = ex;
    int node = blockIdx.x * 256 + t;
    if (node <= N_NODES) row_start[node] = s + ex;  // node==N_NODES lands on N_EDGES
    __syncthreads();

    // scatter src into bucket-local window
    for (int i = s + t; i < e; i += 256) {
        unsigned pk = ebuf[i];
        int pos = s + atomicAdd(&cur[(pk >> 16) & 255], 1);
        csr[pos] = (unsigned short)pk;
    }
}

// ---------------------------------------------------------------------------
// gather (bf16): one wave per node. lane = q(0..7 edge slot) x c(0..7 col-oct).
// Row read = 8 lanes x 16B = 128B; 8 slots x2 unroll = 16 rows in flight.
// ---------------------------------------------------------------------------
__global__ __launch_bounds__(256)
void gather_bf_kernel(const unsigned short* __restrict__ xb,
                      const int* __restrict__ row_start,
                      const unsigned short* __restrict__ csr,
                      unsigned short* __restrict__ mb) {
    const int w = threadIdx.x >> 6;
    const int lane = threadIdx.x & 63;
    const int q = lane >> 3;
    const int c = lane & 7;
    const int n = blockIdx.x * 4 + w;   // grid = 12500*4 = 50000 exactly

    const int rs = row_start[n];
    const int re = row_start[n + 1];

    float s0 = 0.f, s1 = 0.f, s2 = 0.f, s3 = 0.f, s4 = 0.f, s5 = 0.f, s6 = 0.f, s7 = 0.f;

#define ADDROW(node) do {                                              \
        uint4 v_ = *(const uint4*)(xb + (size_t)(node) * FDIM + c * 8);\
        s0 += bf2f_lo(v_.x); s1 += bf2f_hi(v_.x);                      \
        s2 += bf2f_lo(v_.y); s3 += bf2f_hi(v_.y);                      \
        s4 += bf2f_lo(v_.z); s5 += bf2f_hi(v_.z);                      \
        s6 += bf2f_lo(v_.w); s7 += bf2f_hi(v_.w);                      \
    } while (0)

    if (q == 0) ADDROW(n);              // self-loop

    int idx = rs + q;
    for (; idx + 8 < re; idx += 16) {
        int a = csr[idx];
        int b = csr[idx + 8];
        ADDROW(a);
        ADDROW(b);
    }
    for (; idx < re; idx += 8) ADDROW((int)csr[idx]);
#undef ADDROW

#pragma unroll
    for (int off = 8; off < 64; off <<= 1) {
        s0 += __shfl_xor(s0, off, 64);
        s1 += __shfl_xor(s1, off, 64);
        s2 += __shfl_xor(s2, off, 64);
        s3 += __shfl_xor(s3, off, 64);
        s4 += __shfl_xor(s4, off, 64);
        s5 += __shfl_xor(s5, off, 64);
        s6 += __shfl_xor(s6, off, 64);
        s7 += __shfl_xor(s7, off, 64);
    }

    if (q == 0) {
        float inv = 1.0f / (float)(re - rs + 1);
        uint4 o;
        o.x = (unsigned)f2bf(s0 * inv) | ((unsigned)f2bf(s1 * inv) << 16);
        o.y = (unsigned)f2bf(s2 * inv) | ((unsigned)f2bf(s3 * inv) << 16);
        o.z = (unsigned)f2bf(s4 * inv) | ((unsigned)f2bf(s5 * inv) << 16);
        o.w = (unsigned)f2bf(s6 * inv) | ((unsigned)f2bf(s7 * inv) << 16);
        *(uint4*)(mb + (size_t)n * FDIM + c * 8) = o;
    }
}

// ---------------------------------------------------------------------------
// MFMA transform: out = relu( m @ Wl + bl + x @ Wr )
// wave ct computes 16 nodes x cols[ct*16..+15]; A: A[m=lane&15][k=(lane>>4)*8+j];
// C/D: col=lane&15, row=(lane>>4)*4+reg. No LDS. Grid = 3125.
// ---------------------------------------------------------------------------
template <bool OUT_BF16>
__global__ __launch_bounds__(256)
void transform_mfma_kernel(const unsigned short* __restrict__ mb,
                           const unsigned short* __restrict__ xb,
                           const unsigned short* __restrict__ pWl,
                           const float* __restrict__ bl,
                           const unsigned short* __restrict__ pWr,
                           float* __restrict__ out_f32,
                           unsigned short* __restrict__ out_bf) {
    const int ct = threadIdx.x >> 6;
    const int lane = threadIdx.x & 63;
    const int q = lane >> 4;
    const int r = lane & 15;
    const int base = blockIdx.x * 16;

    const size_t arow = (size_t)(base + r) * FDIM;
    short8 am0 = *(const short8*)(mb + arow + q * 8);
    short8 am1 = *(const short8*)(mb + arow + 32 + q * 8);
    short8 ax0 = *(const short8*)(xb + arow + q * 8);
    short8 ax1 = *(const short8*)(xb + arow + 32 + q * 8);

    const short8* pl = (const short8*)pWl;
    const short8* pr = (const short8*)pWr;
    short8 bl0v = pl[(ct * 2 + 0) * 64 + lane];
    short8 bl1v = pl[(ct * 2 + 1) * 64 + lane];
    short8 br0v = pr[(ct * 2 + 0) * 64 + lane];
    short8 br1v = pr[(ct * 2 + 1) * 64 + lane];

    float b = bl[ct * 16 + r];
    f32x4 acc = {b, b, b, b};
    acc = __builtin_amdgcn_mfma_f32_16x16x32_bf16(am0, bl0v, acc, 0, 0, 0);
    acc = __builtin_amdgcn_mfma_f32_16x16x32_bf16(am1, bl1v, acc, 0, 0, 0);
    acc = __builtin_amdgcn_mfma_f32_16x16x32_bf16(ax0, br0v, acc, 0, 0, 0);
    acc = __builtin_amdgcn_mfma_f32_16x16x32_bf16(ax1, br1v, acc, 0, 0, 0);

#pragma unroll
    for (int reg = 0; reg < 4; ++reg) {
        int node = base + q * 4 + reg;
        float v = fmaxf(acc[reg], 0.0f);
        if (OUT_BF16) out_bf[(size_t)node * FDIM + ct * 16 + r] = f2bf(v);
        else          out_f32[(size_t)node * FDIM + ct * 16 + r] = v;
    }
}

// ---------------------------------------------------------------------------
extern "C" void kernel_launch(void* const* d_in, const int* in_sizes, int n_in,
                              void* d_out, int out_size, void* d_ws, size_t ws_size,
                              hipStream_t stream) {
    const float* x0  = (const float*)d_in[0];
    const int*   ei  = (const int*)d_in[1];
    const float* Wl0 = (const float*)d_in[2];
    const float* bl0 = (const float*)d_in[3];
    const float* Wr0 = (const float*)d_in[4];
    const float* Wl1 = (const float*)d_in[5];
    const float* bl1 = (const float*)d_in[6];
    const float* Wr1 = (const float*)d_in[7];
    float* out = (float*)d_out;

    const int* src = ei;            // edge_index[0]
    const int* dst = ei + N_EDGES;  // edge_index[1]

    // workspace layout (padded counters: 1 int per 64B line)
    int* bc_pad   = (int*)d_ws;                       // 256*PAD ints
    int* cur_pad  = bc_pad + 256 * PAD;               // 256*PAD ints
    int* row_start = cur_pad + 256 * PAD;             // 50001 -> pad to 50004
    unsigned* ebuf = (unsigned*)(row_start + 50004);  // 800000 uints
    unsigned short* csr_u16 = (unsigned short*)(ebuf + N_EDGES);  // 800000
    unsigned short* x_bf = csr_u16 + N_EDGES;
    unsigned short* m_bf = x_bf + (size_t)N_NODES * FDIM;
    unsigned short* h_bf = m_bf + (size_t)N_NODES * FDIM;
    unsigned short* pWl0p = h_bf + (size_t)N_NODES * FDIM;
    unsigned short* pWr0p = pWl0p + FDIM * FDIM;
    unsigned short* pWl1p = pWr0p + FDIM * FDIM;
    unsigned short* pWr1p = pWl1p + FDIM * FDIM;

    hipMemsetAsync(bc_pad, 0, 2 * 256 * PAD * sizeof(int), stream);
    preprocess_kernel<<<3911, 256, 0, stream>>>(x0, x_bf, Wl0, Wr0, Wl1, Wr1,
                                                pWl0p, pWr0p, pWl1p, pWr1p,
                                                dst, bc_pad);
    bucket_scatter_kernel<<<(N_EDGES + 1023) / 1024, 256, 0, stream>>>(
        src, dst, bc_pad, cur_pad, ebuf);
    bucket_csr_kernel<<<NBUCK, 256, 0, stream>>>(ebuf, bc_pad, row_start, csr_u16);

    // ---- layer 0 ----
    gather_bf_kernel<<<N_NODES / 4, 256, 0, stream>>>(x_bf, row_start, csr_u16, m_bf);
    transform_mfma_kernel<true><<<N_NODES / 16, 256, 0, stream>>>(
        m_bf, x_bf, pWl0p, bl0, pWr0p, nullptr, h_bf);

    // ---- layer 1 ----
    gather_bf_kernel<<<N_NODES / 4, 256, 0, stream>>>(h_bf, row_start, csr_u16, m_bf);
    transform_mfma_kernel<false><<<N_NODES / 16, 256, 0, stream>>>(
        m_bf, h_bf, pWl1p, bl1, pWr1p, out, nullptr);
}

// Round 10
// 186.780 us; speedup vs baseline: 5.5670x; 1.0671x over previous
//
#include <hip/hip_runtime.h>
#include <hip/hip_bf16.h>

#define N_NODES 50000
#define N_EDGES 800000
#define FDIM 64
#define NBUCK 196          // ceil(50000/256) buckets of 256 nodes
#define PAD 16             // one counter per 64B line

typedef __attribute__((ext_vector_type(8))) short short8;
typedef __attribute__((ext_vector_type(4))) float f32x4;

// fp32 -> bf16 bits, round-to-nearest-even
__device__ __forceinline__ unsigned short f2bf(float f) {
    unsigned u = __float_as_uint(f);
    u += 0x7fffu + ((u >> 16) & 1u);
    return (unsigned short)(u >> 16);
}
__device__ __forceinline__ float bf2f_lo(unsigned u) { return __uint_as_float(u << 16); }
__device__ __forceinline__ float bf2f_hi(unsigned u) { return __uint_as_float(u & 0xffff0000u); }

// exclusive scan of one value per thread across a 256-thread block.
__device__ __forceinline__ int excl_scan_256(int v, int* wtot, int* wincl) {
    const int t = threadIdx.x, lane = t & 63, w = t >> 6;
    int sv = v;
#pragma unroll
    for (int off = 1; off < 64; off <<= 1) {
        int u = __shfl_up(sv, off, 64);
        if (lane >= off) sv += u;
    }
    if (lane == 63) wtot[w] = sv;
    __syncthreads();
    if (w == 0 && lane < 4) {
        int incl = 0;
#pragma unroll
        for (int k = 0; k < 4; ++k)
            if (k <= lane) incl += wtot[k];
        wincl[lane] = incl;
    }
    __syncthreads();
    return (w ? wincl[w - 1] : 0) + sv - v;
}

// ---------------------------------------------------------------------------
// preprocess (fused): [0,3124] convert x0->bf16; [3125,3128] pack weights;
// [3129,3910] bucket histogram of dst>>8 (LDS-aggregated, padded counters).
// ---------------------------------------------------------------------------
__global__ __launch_bounds__(256)
void preprocess_kernel(const float* __restrict__ x0, unsigned short* __restrict__ x_bf,
                       const float* __restrict__ Wl0, const float* __restrict__ Wr0,
                       const float* __restrict__ Wl1, const float* __restrict__ Wr1,
                       unsigned short* __restrict__ pWl0, unsigned short* __restrict__ pWr0,
                       unsigned short* __restrict__ pWl1, unsigned short* __restrict__ pWr1,
                       const int* __restrict__ dst, int* __restrict__ bc_pad) {
    const int b = blockIdx.x;
    if (b < 3125) {                       // convert: 3125*256*4 = 3.2M exactly
        int i = (b * 256 + threadIdx.x) * 4;
        float4 v = *(const float4*)(x0 + i);
        uint2 o;
        o.x = (unsigned)f2bf(v.x) | ((unsigned)f2bf(v.y) << 16);
        o.y = (unsigned)f2bf(v.z) | ((unsigned)f2bf(v.w) << 16);
        *(uint2*)(x_bf + i) = o;
    } else if (b < 3129) {                // pack weights into B-fragment order
        const float* srcs[4] = {Wl0, Wr0, Wl1, Wr1};
        unsigned short* dsts[4] = {pWl0, pWr0, pWl1, pWr1};
        const float* W = srcs[b - 3125];
        unsigned short* P = dsts[b - 3125];
        for (int idx = threadIdx.x; idx < FDIM * FDIM; idx += 256) {
            int j = idx & 7;
            int lane = (idx >> 3) & 63;
            int g = idx >> 9;
            int ct = g >> 1, kk = g & 1;
            int k = kk * 32 + ((lane >> 4) & 3) * 8 + j;
            int col = ct * 16 + (lane & 15);
            P[idx] = f2bf(W[k * FDIM + col]);
        }
    } else {                              // bucket histogram: 782 blocks x 1024 edges
        __shared__ int h[NBUCK];
        if (threadIdx.x < NBUCK) h[threadIdx.x] = 0;
        __syncthreads();
        int e0 = (b - 3129) * 1024;
#pragma unroll
        for (int k = 0; k < 4; ++k) {
            int e = e0 + k * 256 + threadIdx.x;
            if (e < N_EDGES) atomicAdd(&h[dst[e] >> 8], 1);
        }
        __syncthreads();
        if (threadIdx.x < NBUCK) {
            int c = h[threadIdx.x];
            if (c) atomicAdd(&bc_pad[threadIdx.x * PAD], c);
        }
    }
}

// ---------------------------------------------------------------------------
// bucket scatter: rank edges per bucket in LDS, reserve space with one padded
// global atomic per (block,bucket), write packed (dst<<16)|src to ebuf.
// ---------------------------------------------------------------------------
__global__ __launch_bounds__(256)
void bucket_scatter_kernel(const int* __restrict__ src, const int* __restrict__ dst,
                           const int* __restrict__ bc_pad, int* __restrict__ cur_pad,
                           unsigned* __restrict__ ebuf) {
    __shared__ int h[NBUCK];
    __shared__ int base[NBUCK];
    __shared__ int sEx[256];
    __shared__ int wtot[4], wincl[4];
    const int t = threadIdx.x;

    int v = (t < NBUCK) ? bc_pad[t * PAD] : 0;
    sEx[t] = excl_scan_256(v, wtot, wincl);
    if (t < NBUCK) h[t] = 0;
    __syncthreads();

    int e0 = blockIdx.x * 1024;
    int bk[4], rk[4]; unsigned pk[4];
#pragma unroll
    for (int k = 0; k < 4; ++k) {
        int e = e0 + k * 256 + t;
        if (e < N_EDGES) {
            int d = dst[e];
            bk[k] = d >> 8;
            pk[k] = ((unsigned)d << 16) | (unsigned)src[e];
            rk[k] = atomicAdd(&h[bk[k]], 1);
        } else bk[k] = -1;
    }
    __syncthreads();
    if (t < NBUCK) {
        int c = h[t];
        base[t] = c ? (sEx[t] + atomicAdd(&cur_pad[t * PAD], c)) : 0;
    }
    __syncthreads();
#pragma unroll
    for (int k = 0; k < 4; ++k)
        if (bk[k] >= 0) ebuf[base[bk[k]] + rk[k]] = pk[k];
}

// ---------------------------------------------------------------------------
// bucket CSR finalize: one block per bucket (256 nodes). Replaces count+scan+fill.
// ---------------------------------------------------------------------------
__global__ __launch_bounds__(256)
void bucket_csr_kernel(const unsigned* __restrict__ ebuf, const int* __restrict__ bc_pad,
                       int* __restrict__ row_start, unsigned short* __restrict__ csr) {
    __shared__ int sEx[257];
    __shared__ int cnt[256];
    __shared__ int cur[256];
    __shared__ int wtot[4], wincl[4];
    const int t = threadIdx.x;

    int v = (t < NBUCK) ? bc_pad[t * PAD] : 0;
    sEx[t] = excl_scan_256(v, wtot, wincl);
    if (t == 255) sEx[256] = sEx[255];
    cnt[t] = 0;
    __syncthreads();
    const int s = sEx[blockIdx.x];
    const int e = sEx[blockIdx.x + 1];

    for (int i = s + t; i < e; i += 256)
        atomicAdd(&cnt[(ebuf[i] >> 16) & 255], 1);
    __syncthreads();

    int c = cnt[t];
    int ex = excl_scan_256(c, wtot, wincl);
    cur[t] = ex;
    int node = blockIdx.x * 256 + t;
    if (node <= N_NODES) row_start[node] = s + ex;
    __syncthreads();

    for (int i = s + t; i < e; i += 256) {
        unsigned pk = ebuf[i];
        int pos = s + atomicAdd(&cur[(pk >> 16) & 255], 1);
        csr[pos] = (unsigned short)pk;
    }
}

// ---------------------------------------------------------------------------
// fused SAGE layer: block = 256 (4 waves), 16 nodes. Grid 3125 (x16 = 50000).
// Phase 1 (gather): wave w handles nodes base+4w..+3; lane = q(8 edge slots)
//   x c(8 col-octs); 16 rows in flight; mean + self rows staged in LDS (bf16),
//   octs XOR-swizzled by row&7 so phase-2 A-fragment reads are 2-way (free).
// Phase 2 (MFMA): wave ct does cols [16ct,16ct+16): A from LDS, B pre-packed,
//   C/D: col=lane&15, row=(lane>>4)*4+reg. out = relu(mean@Wl + bl + x@Wr).
// ---------------------------------------------------------------------------
template <bool OUT_BF16>
__global__ __launch_bounds__(256)
void sage_fused_kernel(const unsigned short* __restrict__ xb,
                       const int* __restrict__ row_start,
                       const unsigned short* __restrict__ csr,
                       const unsigned short* __restrict__ pWl,
                       const float* __restrict__ bl,
                       const unsigned short* __restrict__ pWr,
                       float* __restrict__ out_f32,
                       unsigned short* __restrict__ out_bf) {
    __shared__ __align__(16) unsigned short smean[16][FDIM];
    __shared__ __align__(16) unsigned short sxs[16][FDIM];

    const int w = threadIdx.x >> 6;
    const int lane = threadIdx.x & 63;
    const int q = lane >> 3;          // edge slot 0..7
    const int c = lane & 7;           // col-oct 0..7
    const int base = blockIdx.x * 16;

    // ---- phase 1: gather 4 nodes per wave ----
#pragma unroll
    for (int i = 0; i < 4; ++i) {
        const int r = (w << 2) + i;   // local row 0..15
        const int n = base + r;
        const int rs = row_start[n];
        const int re = row_start[n + 1];
        const int po = (c ^ (r & 7)) * 8;   // swizzled physical oct offset

        float s0 = 0.f, s1 = 0.f, s2 = 0.f, s3 = 0.f,
              s4 = 0.f, s5 = 0.f, s6 = 0.f, s7 = 0.f;

#define ADDROW(node) do {                                               \
        uint4 v_ = *(const uint4*)(xb + (size_t)(node) * FDIM + c * 8); \
        s0 += bf2f_lo(v_.x); s1 += bf2f_hi(v_.x);                       \
        s2 += bf2f_lo(v_.y); s3 += bf2f_hi(v_.y);                       \
        s4 += bf2f_lo(v_.z); s5 += bf2f_hi(v_.z);                       \
        s6 += bf2f_lo(v_.w); s7 += bf2f_hi(v_.w);                       \
    } while (0)

        if (q == 0) {                  // self row: accumulate + stage to LDS
            uint4 v_ = *(const uint4*)(xb + (size_t)n * FDIM + c * 8);
            *(uint4*)(&sxs[r][po]) = v_;
            s0 += bf2f_lo(v_.x); s1 += bf2f_hi(v_.x);
            s2 += bf2f_lo(v_.y); s3 += bf2f_hi(v_.y);
            s4 += bf2f_lo(v_.z); s5 += bf2f_hi(v_.z);
            s6 += bf2f_lo(v_.w); s7 += bf2f_hi(v_.w);
        }

        int idx = rs + q;
        for (; idx + 8 < re; idx += 16) {
            int a = csr[idx];
            int b2 = csr[idx + 8];
            ADDROW(a);
            ADDROW(b2);
        }
        for (; idx < re; idx += 8) ADDROW((int)csr[idx]);
#undef ADDROW

#pragma unroll
        for (int off = 8; off < 64; off <<= 1) {
            s0 += __shfl_xor(s0, off, 64);
            s1 += __shfl_xor(s1, off, 64);
            s2 += __shfl_xor(s2, off, 64);
            s3 += __shfl_xor(s3, off, 64);
            s4 += __shfl_xor(s4, off, 64);
            s5 += __shfl_xor(s5, off, 64);
            s6 += __shfl_xor(s6, off, 64);
            s7 += __shfl_xor(s7, off, 64);
        }

        if (q == 0) {
            float inv = 1.0f / (float)(re - rs + 1);
            uint4 o;
            o.x = (unsigned)f2bf(s0 * inv) | ((unsigned)f2bf(s1 * inv) << 16);
            o.y = (unsigned)f2bf(s2 * inv) | ((unsigned)f2bf(s3 * inv) << 16);
            o.z = (unsigned)f2bf(s4 * inv) | ((unsigned)f2bf(s5 * inv) << 16);
            o.w = (unsigned)f2bf(s6 * inv) | ((unsigned)f2bf(s7 * inv) << 16);
            *(uint4*)(&smean[r][po]) = o;
        }
    }
    __syncthreads();

    // ---- phase 2: MFMA, wave ct = w handles cols [16w, 16w+16) ----
    const int ct = w;
    const int qq = lane >> 4;
    const int rr = lane & 15;

    short8 am0 = *(const short8*)(&smean[rr][((0 + qq) ^ (rr & 7)) * 8]);
    short8 am1 = *(const short8*)(&smean[rr][((4 + qq) ^ (rr & 7)) * 8]);
    short8 ax0 = *(const short8*)(&sxs[rr][((0 + qq) ^ (rr & 7)) * 8]);
    short8 ax1 = *(const short8*)(&sxs[rr][((4 + qq) ^ (rr & 7)) * 8]);

    const short8* pl = (const short8*)pWl;
    const short8* pr = (const short8*)pWr;
    short8 bl0v = pl[(ct * 2 + 0) * 64 + lane];
    short8 bl1v = pl[(ct * 2 + 1) * 64 + lane];
    short8 br0v = pr[(ct * 2 + 0) * 64 + lane];
    short8 br1v = pr[(ct * 2 + 1) * 64 + lane];

    float b = bl[ct * 16 + rr];
    f32x4 acc = {b, b, b, b};
    acc = __builtin_amdgcn_mfma_f32_16x16x32_bf16(am0, bl0v, acc, 0, 0, 0);
    acc = __builtin_amdgcn_mfma_f32_16x16x32_bf16(am1, bl1v, acc, 0, 0, 0);
    acc = __builtin_amdgcn_mfma_f32_16x16x32_bf16(ax0, br0v, acc, 0, 0, 0);
    acc = __builtin_amdgcn_mfma_f32_16x16x32_bf16(ax1, br1v, acc, 0, 0, 0);

#pragma unroll
    for (int reg = 0; reg < 4; ++reg) {
        int node = base + qq * 4 + reg;
        float v = fmaxf(acc[reg], 0.0f);
        if (OUT_BF16) out_bf[(size_t)node * FDIM + ct * 16 + rr] = f2bf(v);
        else          out_f32[(size_t)node * FDIM + ct * 16 + rr] = v;
    }
}

// ---------------------------------------------------------------------------
extern "C" void kernel_launch(void* const* d_in, const int* in_sizes, int n_in,
                              void* d_out, int out_size, void* d_ws, size_t ws_size,
                              hipStream_t stream) {
    const float* x0  = (const float*)d_in[0];
    const int*   ei  = (const int*)d_in[1];
    const float* Wl0 = (const float*)d_in[2];
    const float* bl0 = (const float*)d_in[3];
    const float* Wr0 = (const float*)d_in[4];
    const float* Wl1 = (const float*)d_in[5];
    const float* bl1 = (const float*)d_in[6];
    const float* Wr1 = (const float*)d_in[7];
    float* out = (float*)d_out;

    const int* src = ei;            // edge_index[0]
    const int* dst = ei + N_EDGES;  // edge_index[1]

    // workspace layout (padded counters: 1 int per 64B line)
    int* bc_pad    = (int*)d_ws;                      // 256*PAD ints
    int* cur_pad   = bc_pad + 256 * PAD;              // 256*PAD ints
    int* row_start = cur_pad + 256 * PAD;             // 50001 -> pad to 50004
    unsigned* ebuf = (unsigned*)(row_start + 50004);  // 800000 uints
    unsigned short* csr_u16 = (unsigned short*)(ebuf + N_EDGES);  // 800000
    unsigned short* x_bf = csr_u16 + N_EDGES;
    unsigned short* h_bf = x_bf + (size_t)N_NODES * FDIM;
    unsigned short* pWl0p = h_bf + (size_t)N_NODES * FDIM;
    unsigned short* pWr0p = pWl0p + FDIM * FDIM;
    unsigned short* pWl1p = pWr0p + FDIM * FDIM;
    unsigned short* pWr1p = pWl1p + FDIM * FDIM;

    hipMemsetAsync(bc_pad, 0, 2 * 256 * PAD * sizeof(int), stream);
    preprocess_kernel<<<3911, 256, 0, stream>>>(x0, x_bf, Wl0, Wr0, Wl1, Wr1,
                                                pWl0p, pWr0p, pWl1p, pWr1p,
                                                dst, bc_pad);
    bucket_scatter_kernel<<<(N_EDGES + 1023) / 1024, 256, 0, stream>>>(
        src, dst, bc_pad, cur_pad, ebuf);
    bucket_csr_kernel<<<NBUCK, 256, 0, stream>>>(ebuf, bc_pad, row_start, csr_u16);

    // ---- layer 0 (out: bf16 h) ----
    sage_fused_kernel<true><<<N_NODES / 16, 256, 0, stream>>>(
        x_bf, row_start, csr_u16, pWl0p, bl0, pWr0p, nullptr, h_bf);
    // ---- layer 1 (out: fp32 d_out) ----
    sage_fused_kernel<false><<<N_NODES / 16, 256, 0, stream>>>(
        h_bf, row_start, csr_u16, pWl1p, bl1, pWr1p, out, nullptr);
}